// Round 13
// baseline (417.825 us; speedup 1.0000x reference)
//
#include <hip/hip_runtime.h>

// LorentzBlock: B=2, L=2048, D=768, H=12, DH=64, DFF=3072
// R23: 1-barrier depth-3 GEMM loop (stage-at-END-of-iter) for the
// grid-capped GEMMs (ffn2/QKV/Wo). ffn2's wall ~1430cy/iter has TWO
// s_barriers; the 2nd only protects buffer reuse at distance 2. Depth-3
// ring + stage AFTER compute makes the overwritten buffer (t-1's, distance
// 3) provably reader-free at stage time -> 2nd barrier deleted.
// vmcnt before barrier keeps the collective "tile t landed" guarantee.
// FFN1 keeps 2-barrier/32KB (needs 5 blocks/CU; 48KB would halve it).
// Base = R22 (411.3us): flash chunk-4 fp16 partials, qcorr-fused QKV,
// XCD swizzle, ffn2 x4 / Wo x2 128^2 splits.

typedef unsigned short u16;
typedef __bf16 bfrag __attribute__((ext_vector_type(8)));
typedef float f32x4 __attribute__((ext_vector_type(4)));

#define MFMA(a, b, c) __builtin_amdgcn_mfma_f32_16x16x32_bf16(a, b, c, 0, 0, 0)
#define NEG_BIG (-30000.0f)
#define ASYNC16(g, l)                                                        \
  __builtin_amdgcn_global_load_lds(                                          \
      (const __attribute__((address_space(1))) unsigned int*)(g),            \
      (__attribute__((address_space(3))) unsigned int*)(l), 16, 0, 0)

__device__ __forceinline__ float bf2f(u16 u) {
  unsigned int v = ((unsigned int)u) << 16;
  float f; __builtin_memcpy(&f, &v, 4); return f;
}
__device__ __forceinline__ u16 f2bf(float f) {
  unsigned int v; __builtin_memcpy(&v, &f, 4);
  v += 0x7fffu + ((v >> 16) & 1u);   // RNE
  return (u16)(v >> 16);
}
__device__ __forceinline__ u16 f2h(float f) {
  _Float16 h = (_Float16)f; u16 u; __builtin_memcpy(&u, &h, 2); return u;
}
__device__ __forceinline__ float h2f(u16 u) {
  _Float16 h; __builtin_memcpy(&h, &u, 2); return (float)h;
}
__device__ __forceinline__ bfrag ldfrag(const u16* p) {
  bfrag v; __builtin_memcpy(&v, p, 16); return v;
}

// XCD-chunked bijective swizzle of the linear workgroup id. Requires
// nwg % 8 == 0 (all call sites comply); identity fallback otherwise.
__device__ __forceinline__ int xcd_work_id() {
  const int nx = gridDim.x, ny = gridDim.y;
  const int nwg = nx * ny * gridDim.z;
  const int orig = blockIdx.x + nx * (blockIdx.y + ny * blockIdx.z);
  if (nwg & 7) return orig;
  return (orig & 7) * (nwg >> 3) + (orig >> 3);
}

// ---------------------------------------------------------------------------
// Mask canonicalization -> float[768].
// ---------------------------------------------------------------------------
__global__ __launch_bounds__(256) void mask_conv_k(const void* __restrict__ mask,
                                                   float* __restrict__ mfl) {
  __shared__ int msh;
  if (threadIdx.x == 0) msh = 0;
  __syncthreads();
  const unsigned int* w = (const unsigned int*)mask;
  if (threadIdx.x < 192) {
    const unsigned int v = w[threadIdx.x];
    if ((v & 0xFFFFu) == 0x3F80u) atomicOr(&msh, 4);
    else if (v == 0x3F800000u) atomicOr(&msh, 2);
    else if (v >= 2u) atomicOr(&msh, 1);
  }
  __syncthreads();
  const int m = msh;
  const int mode = (m & 4) ? 3 : (m & 2) ? 2 : (m & 1) ? 1 : 0;
  for (int i = threadIdx.x; i < 768; i += 256) {
    int b;
    if (mode == 3) b = ((const u16*)mask)[i] != 0;
    else if (mode == 2) b = ((const float*)mask)[i] != 0.0f;
    else if (mode == 1) b = ((const unsigned char*)mask)[i] != 0;
    else b = ((const int*)mask)[i] != 0;
    mfl[i] = (float)b;
  }
}

// ---------------------------------------------------------------------------
// Convert fp32 weight segments -> bf16 arena. mmode: 0 none, 1 *m[k],
// 2 *(1-m[k]) with k = i % 768 (mask fold for w1_t / w1_s).
// ---------------------------------------------------------------------------
struct Segs {
  const void* src[14];
  int off[14];
  int n[14];
  int mmode[14];
};

__global__ __launch_bounds__(256) void convert_k(Segs segs, u16* __restrict__ dstb,
                                                 const float* __restrict__ mfl) {
  const int seg = blockIdx.y;
  const int n = segs.n[seg];
  const int mm = segs.mmode[seg];
  u16* dst = dstb + segs.off[seg];
  const float* src = (const float*)segs.src[seg];
  for (int i = (blockIdx.x * 256 + threadIdx.x) * 4; i < n; i += gridDim.x * 1024) {
    float4 v;
    __builtin_memcpy(&v, src + i, 16);
    if (mm) {
      const int k = i % 768;
      float m0 = mfl[k], m1 = mfl[k + 1], m2 = mfl[k + 2], m3 = mfl[k + 3];
      if (mm == 2) { m0 = 1.f - m0; m1 = 1.f - m1; m2 = 1.f - m2; m3 = 1.f - m3; }
      v.x *= m0; v.y *= m1; v.z *= m2; v.w *= m3;
    }
    dst[i] = f2bf(v.x); dst[i + 1] = f2bf(v.y);
    dst[i + 2] = f2bf(v.z); dst[i + 3] = f2bf(v.w);
  }
}

// ---------------------------------------------------------------------------
// Minkowski LayerNorm. fp32 input, bf16 output. Optionally copies the raw
// input row to Xcopy (fp32) -- seeds d_out with x for the Wo split-K atomics.
// ---------------------------------------------------------------------------
__global__ __launch_bounds__(256) void mink_norm_k(
    const float* __restrict__ X, const float* __restrict__ mf,
    const u16* __restrict__ w, const u16* __restrict__ bias,
    u16* __restrict__ Y, float* __restrict__ Xcopy) {
  __shared__ float red[8];
  const int row = blockIdx.x, tid = threadIdx.x;
  const int wid = tid >> 6, lane = tid & 63;
  const size_t roff = (size_t)row * 768;

  float xv[3], mv[3];
  int idx[3];
#pragma unroll
  for (int i = 0; i < 3; i++) {
    idx[i] = tid + i * 256;
    xv[i] = X[roff + idx[i]];
    mv[i] = mf[idx[i]];
  }
  if (Xcopy) {
#pragma unroll
    for (int i = 0; i < 3; i++) Xcopy[roff + idx[i]] = xv[i];
  }
  float s = xv[0] + xv[1] + xv[2];
#pragma unroll
  for (int o = 32; o >= 1; o >>= 1) s += __shfl_xor(s, o, 64);
  if (lane == 0) red[wid] = s;
  __syncthreads();
  const float mean = (red[0] + red[1] + red[2] + red[3]) * (1.0f / 768.0f);
  __syncthreads();

  float xc[3], ss = 0.0f, sm = 0.0f;
#pragma unroll
  for (int i = 0; i < 3; i++) {
    xc[i] = xv[i] - mean;
    ss += xc[i] * xc[i];
    sm += xc[i] * xc[i] * mv[i];
  }
#pragma unroll
  for (int o = 32; o >= 1; o >>= 1) {
    ss += __shfl_xor(ss, o, 64);
    sm += __shfl_xor(sm, o, 64);
  }
  if (lane == 0) { red[wid] = ss; red[4 + wid] = sm; }
  __syncthreads();
  const float sumsq = red[0] + red[1] + red[2] + red[3];
  const float summ = red[4] + red[5] + red[6] + red[7];
  const float var = sumsq * (1.0f / 768.0f);
  const float eta = sumsq - 2.0f * summ;
  const float rs = 1.0f / sqrtf(var + 1e-5f);
  const float re = 1.0f / sqrtf(fabsf(eta) + 1e-5f);

#pragma unroll
  for (int i = 0; i < 3; i++) {
    const float xn = xc[i] * 0.5f * (rs + re);
    Y[roff + idx[i]] = f2bf(bf2f(w[idx[i]]) * xn + bf2f(bias[idx[i]]));
  }
}

// ---------------------------------------------------------------------------
// 128x128 MFMA GEMM core, templated on LDS buffer count NB:
//  NB==2: R16 2-barrier depth-2 counted-vmcnt loop (32KB) -- FFN1.
//  NB==3: 1-barrier depth-3, stage-at-end (48KB) -- ffn2/QKV/Wo:
//    iter t: vmcnt(4) [own tile-t landed]; s_barrier [collective: tile t in
//    LDS + compute(t-1) done everywhere]; ds_read+MFMA(buf t%3);
//    stage(t+2 -> buf (t+2)%3)  [overwrites t-1's buf: readers provably
//    done because stage is sequenced after barrier(t)].
// ---------------------------------------------------------------------------
template <int NB>
__device__ __forceinline__ void gemm128_loop(
    const u16* __restrict__ Ab, const u16* __restrict__ Wb2,
    int K, int lda, int ldb, u16 (*As)[32], u16 (*Bs)[32], f32x4 acc[4][4]) {
  const int tid = threadIdx.x;
  const int wid = tid >> 6, lane = tid & 63;
  const int lr = lane & 15, lq = lane >> 4;
  const int srow = wid * 32 + (lane >> 2);
  const int scol = (lane & 3) * 8;
  const u16* ga0 = Ab + (size_t)srow * lda + scol;
  const u16* ga1 = Ab + (size_t)(srow + 16) * lda + scol;
  const u16* gb0 = Wb2 + (size_t)srow * ldb + scol;
  const u16* gb1 = Wb2 + (size_t)(srow + 16) * ldb + scol;
  const int wr = (wid >> 1) * 64, wc = (wid & 1) * 64;
  const int nt = K >> 5;

#define STAGE16(dbuf, k0)                                                    \
  {                                                                          \
    u16* _a0 = &As[(dbuf) * 128 + wid * 32][0];                              \
    u16* _a1 = &As[(dbuf) * 128 + wid * 32 + 16][0];                         \
    u16* _b0 = &Bs[(dbuf) * 128 + wid * 32][0];                              \
    u16* _b1 = &Bs[(dbuf) * 128 + wid * 32 + 16][0];                         \
    ASYNC16(ga0 + (k0), _a0);                                                \
    ASYNC16(ga1 + (k0), _a1);                                                \
    ASYNC16(gb0 + (k0), _b0);                                                \
    ASYNC16(gb1 + (k0), _b1);                                                \
  }

  if constexpr (NB == 2) {
    STAGE16(0, 0);
    for (int t = 0; t < nt; ++t) {
      const int cur = t & 1;
      if (t + 1 < nt) {
        STAGE16(cur ^ 1, (t + 1) << 5);
        __builtin_amdgcn_sched_barrier(0);
        asm volatile("s_waitcnt vmcnt(4)" ::: "memory");
      } else {
        asm volatile("s_waitcnt vmcnt(0)" ::: "memory");
      }
      __builtin_amdgcn_s_barrier();
      __builtin_amdgcn_sched_barrier(0);
      bfrag af[4], bf4[4];
#pragma unroll
      for (int i = 0; i < 4; i++)
        af[i] = ldfrag(&As[cur * 128 + wr + i * 16 + lr][lq * 8]);
#pragma unroll
      for (int j = 0; j < 4; j++)
        bf4[j] = ldfrag(&Bs[cur * 128 + wc + j * 16 + lr][lq * 8]);
#pragma unroll
      for (int i = 0; i < 4; i++)
#pragma unroll
        for (int j = 0; j < 4; j++)
          acc[i][j] = MFMA(af[i], bf4[j], acc[i][j]);
      asm volatile("s_waitcnt lgkmcnt(0)" ::: "memory");
      __builtin_amdgcn_sched_barrier(0);
      __builtin_amdgcn_s_barrier();
    }
  } else {
    // 1-barrier depth-3, stage-at-end
    STAGE16(0, 0);
    if (nt > 1) STAGE16(1, 32);
    for (int t = 0; t < nt; ++t) {
      const int cur = t % 3;
      if (t + 1 < nt)
        asm volatile("s_waitcnt vmcnt(4)" ::: "memory");
      else
        asm volatile("s_waitcnt vmcnt(0)" ::: "memory");
      __builtin_amdgcn_s_barrier();
      __builtin_amdgcn_sched_barrier(0);
      bfrag af[4], bf4[4];
#pragma unroll
      for (int i = 0; i < 4; i++)
        af[i] = ldfrag(&As[cur * 128 + wr + i * 16 + lr][lq * 8]);
#pragma unroll
      for (int j = 0; j < 4; j++)
        bf4[j] = ldfrag(&Bs[cur * 128 + wc + j * 16 + lr][lq * 8]);
#pragma unroll
      for (int i = 0; i < 4; i++)
#pragma unroll
        for (int j = 0; j < 4; j++)
          acc[i][j] = MFMA(af[i], bf4[j], acc[i][j]);
      __builtin_amdgcn_sched_barrier(0);
      if (t + 2 < nt) STAGE16((t + 2) % 3, (t + 2) << 5);
    }
  }
#undef STAGE16
}

// ---------------------------------------------------------------------------
// Fused multi-segment GEMM, bf16 out: C_seg = epi(A @ Wseg^T).
// epi: 0 none, 1 Lorentz-Q correction (fused qcorr), 2 gelu, 3 silu.
// NB selects the loop variant (QKV: 3, FFN1: 2).
// ---------------------------------------------------------------------------
struct GSeg { const u16* W; u16* C; int ldc; int nblk; int epi; };
struct GArgs { GSeg s[3]; };

template <int NB>
__global__ __launch_bounds__(256) void gemm128_fused(
    const u16* __restrict__ A, int lda, int K, GArgs args,
    const float* __restrict__ mfl) {
  __shared__ __align__(16) u16 As[NB * 128][32];
  __shared__ __align__(16) u16 Bs[NB * 128][32];
  const int w = xcd_work_id();
  int cb = w % gridDim.x, seg = 0;
  const int by = w / gridDim.x;
  while (cb >= args.s[seg].nblk) { cb -= args.s[seg].nblk; seg++; }
  const GSeg g = args.s[seg];
  const int rowb = by * 128, colb = cb * 128;
  f32x4 acc[4][4] = {};
  gemm128_loop<NB>(A + (size_t)rowb * lda, g.W + (size_t)colb * K, K, lda, K,
                   As, Bs, acc);

  const int lane = threadIdx.x & 63, wid = threadIdx.x >> 6;
  const int lr = lane & 15, lq = lane >> 4;
  const int wr = (wid >> 1) * 64, wc = (wid & 1) * 64;

  if (g.epi == 1) {
    // fused Lorentz Q correction (head-aligned 64-col block per wave)
    const int cb64 = colb + wc;
    float mj[4];
#pragma unroll
    for (int j = 0; j < 4; j++) mj[j] = mfl[cb64 + j * 16 + lr];
#pragma unroll
    for (int i = 0; i < 4; i++)
#pragma unroll
      for (int r = 0; r < 4; r++) {
        float p2 = 0.0f, pm2 = 0.0f;
#pragma unroll
        for (int j = 0; j < 4; j++) {
          const float v = acc[i][j][r];
          p2 += v * v;
          pm2 += v * v * mj[j];
        }
#pragma unroll
        for (int off = 8; off >= 1; off >>= 1) {
          p2 += __shfl_xor(p2, off, 64);
          pm2 += __shfl_xor(pm2, off, 64);
        }
        const float qn = sqrtf(p2), qtn = sqrtf(pm2);
        const float sf = (qtn > 1e-6f) ? qn / fmaxf(qtn, 1e-8f) : 0.0f;
        const int row = rowb + wr + i * 16 + lq * 4 + r;
#pragma unroll
        for (int j = 0; j < 4; j++) {
          const int col = cb64 + j * 16 + lr;
          const float v = acc[i][j][r] * (1.0f - 0.5f * sf * mj[j]) * 0.125f;
          g.C[(size_t)row * g.ldc + col] = f2bf(v);
        }
      }
    return;
  }

#pragma unroll
  for (int i = 0; i < 4; i++)
#pragma unroll
    for (int j = 0; j < 4; j++)
#pragma unroll
      for (int r = 0; r < 4; r++) {
        const int row = rowb + wr + i * 16 + lq * 4 + r;
        const int col = colb + wc + j * 16 + lr;
        float v = acc[i][j][r];
        if (g.epi == 2) v = 0.5f * v * (1.0f + erff(v * 0.70710678118654752f));
        else if (g.epi == 3) v = v / (1.0f + __expf(-v));
        g.C[(size_t)row * g.ldc + col] = f2bf(v);
      }
}

// ---------------------------------------------------------------------------
// Wo projection split-K x2 (128^2 tiles, 1-barrier loop): Out += att@Wo^T.
// Out (d_out) holds x. grid (6,32,2), XCD-swizzled.
// ---------------------------------------------------------------------------
__global__ __launch_bounds__(256) void gemm128_wo_splitk(
    const u16* __restrict__ A, const u16* __restrict__ W,
    float* __restrict__ Out) {
  __shared__ __align__(16) u16 As[384][32];
  __shared__ __align__(16) u16 Bs[384][32];
  const int w = xcd_work_id();
  const int bx = w % gridDim.x;
  const int by = (w / gridDim.x) % gridDim.y;
  const int z = w / (gridDim.x * gridDim.y);
  const int rowb = by * 128, colb = bx * 128;
  f32x4 acc[4][4] = {};
  gemm128_loop<3>(A + (size_t)rowb * 768 + z * 384,
                  W + (size_t)colb * 768 + z * 384, 384, 768, 768,
                  As, Bs, acc);

  const int lane = threadIdx.x & 63, wid = threadIdx.x >> 6;
  const int lr = lane & 15, lq = lane >> 4;
  const int wr = (wid >> 1) * 64, wc = (wid & 1) * 64;
#pragma unroll
  for (int i = 0; i < 4; i++)
#pragma unroll
    for (int j = 0; j < 4; j++)
#pragma unroll
      for (int r = 0; r < 4; r++) {
        const int row = rowb + wr + i * 16 + lq * 4 + r;
        const int col = colb + wc + j * 16 + lr;
        atomicAdd(&Out[(size_t)row * 768 + col], acc[i][j][r]);
      }
}

// ---------------------------------------------------------------------------
// FFN2 split-K x4 (128^2 tiles, 1-barrier loop): Out += 0.5*partial.
// Out holds x1. grid (6,32,4), XCD-swizzled.
// ---------------------------------------------------------------------------
__global__ __launch_bounds__(256) void ffn2_splitk(
    const u16* __restrict__ H1, const u16* __restrict__ Ht,
    const u16* __restrict__ Hs, const u16* __restrict__ W2,
    const u16* __restrict__ W2t, const u16* __restrict__ W2s,
    float* __restrict__ Out) {
  __shared__ __align__(16) u16 As[384][32];
  __shared__ __align__(16) u16 Bs[384][32];
  const int w = xcd_work_id();
  const int bx = w % gridDim.x;
  const int by = (w / gridDim.x) % gridDim.y;
  const int z = w / (gridDim.x * gridDim.y);
  const int rowb = by * 128, colb = bx * 128;
  f32x4 acc[4][4] = {};
  if (z == 0)
    gemm128_loop<3>(H1 + (size_t)rowb * 3072, W2 + (size_t)colb * 3072,
                    1536, 3072, 3072, As, Bs, acc);
  else if (z == 1)
    gemm128_loop<3>(H1 + (size_t)rowb * 3072 + 1536,
                    W2 + (size_t)colb * 3072 + 1536,
                    1536, 3072, 3072, As, Bs, acc);
  else if (z == 2)
    gemm128_loop<3>(Ht + (size_t)rowb * 1536, W2t + (size_t)colb * 1536,
                    1536, 1536, 1536, As, Bs, acc);
  else
    gemm128_loop<3>(Hs + (size_t)rowb * 1536, W2s + (size_t)colb * 1536,
                    1536, 1536, 1536, As, Bs, acc);

  const int lane = threadIdx.x & 63, wid = threadIdx.x >> 6;
  const int lr = lane & 15, lq = lane >> 4;
  const int wr = (wid >> 1) * 64, wc = (wid & 1) * 64;
#pragma unroll
  for (int i = 0; i < 4; i++)
#pragma unroll
    for (int j = 0; j < 4; j++)
#pragma unroll
      for (int r = 0; r < 4; r++) {
        const int row = rowb + wr + i * 16 + lq * 4 + r;
        const int col = colb + wc + j * 16 + lr;
        atomicAdd(&Out[(size_t)row * 768 + col], 0.5f * acc[i][j][r]);
      }
}

// ---------------------------------------------------------------------------
// Flash attention producer, causal, KV-split chunk=4 (R22). QBLK=64, 4 waves.
// Per bh: 144 blocks. qt<4: writes final bf16. qt>=4: fp16 O partial +
// fp32 (m,l) at slot s = bh*140 + off(qt) + c.
// ---------------------------------------------------------------------------
__global__ __launch_bounds__(256) void flash_attn_k(
    const u16* __restrict__ Qc, const u16* __restrict__ Kb,
    const u16* __restrict__ Vb, u16* __restrict__ O,
    u16* __restrict__ Pn, u16* __restrict__ Ph, float* __restrict__ Lm) {
  __shared__ __align__(16) u16 Ks[64][40];
  __shared__ __align__(16) u16 Vt[64][72];
  __shared__ __align__(16) u16 Ps[4][16][72];
  const int tid = threadIdx.x, wid = tid >> 6, lane = tid & 63;
  const int lr = lane & 15, lq = lane >> 4;

  // decode blockIdx.x -> (qt, c); qt descending so long chunks launch first
  int bx = blockIdx.x, qt = 0, c = 0;
  for (int q = 31; q >= 0; --q) {
    const int nc = (q < 4) ? 1 : (q / 4 + 1);
    if (bx < nc) { qt = q; c = bx; break; }
    bx -= nc;
  }
  const int nt = qt + 1;
  const int t0 = c * 4;
  const int t1 = (t0 + 4 < nt) ? t0 + 4 : nt;

  const int qb = qt * 64;
  const int bh = blockIdx.y;
  const int b = bh / 12, h = bh % 12;
  const int q0 = qb + wid * 16;
  const size_t base = (size_t)b * 2048 * 768 + h * 64;

  bfrag aq[2];
  aq[0] = ldfrag(Qc + base + (size_t)(q0 + lr) * 768 + lq * 8);
  aq[1] = ldfrag(Qc + base + (size_t)(q0 + lr) * 768 + 32 + lq * 8);

  f32x4 o[4] = {};
  float mrow[4] = {NEG_BIG, NEG_BIG, NEG_BIG, NEG_BIG};
  float lrow[4] = {0.0f, 0.0f, 0.0f, 0.0f};

  const int krow = tid >> 3;        // 0..31
  const int kcol = (tid & 7) * 8;
  const int vkey = tid & 31;
  const int vdg = tid >> 5;         // 0..7

  const u16* kp = Kb + base + (size_t)(t0 * 64 + krow) * 768 + kcol;
  const u16* vp = Vb + base + (size_t)(t0 * 64 + vkey) * 768 + vdg * 8;

  uint4 kv0, kv1, vv0, vv1;
  __builtin_memcpy(&kv0, kp, 16);
  __builtin_memcpy(&kv1, kp + (size_t)32 * 768, 16);
  __builtin_memcpy(&vv0, vp, 16);
  __builtin_memcpy(&vv1, vp + (size_t)32 * 768, 16);

  for (int kt = t0; kt < t1; kt++) {
    __syncthreads();
    __builtin_memcpy(&Ks[krow][kcol], &kv0, 16);
    __builtin_memcpy(&Ks[krow + 32][kcol], &kv1, 16);
    {
      union { uint4 u; u16 s[8]; } a, b2;
      a.u = vv0; b2.u = vv1;
#pragma unroll
      for (int j = 0; j < 8; j++) {
        Vt[vdg * 8 + j][vkey] = a.s[j];
        Vt[vdg * 8 + j][vkey + 32] = b2.s[j];
      }
    }
    __syncthreads();
    if (kt + 1 < t1) {
      const size_t koff = (size_t)(kt + 1 - t0) * 64 * 768;
      __builtin_memcpy(&kv0, kp + koff, 16);
      __builtin_memcpy(&kv1, kp + koff + (size_t)32 * 768, 16);
      __builtin_memcpy(&vv0, vp + koff, 16);
      __builtin_memcpy(&vv1, vp + koff + (size_t)32 * 768, 16);
    }

    const int kbk = kt * 64;
    {
      f32x4 s4[4] = {};
#pragma unroll
      for (int kg = 0; kg < 2; kg++) {
#pragma unroll
        for (int cc = 0; cc < 4; cc++) {
          bfrag bk = ldfrag(&Ks[cc * 16 + lr][kg * 32 + lq * 8]);
          s4[cc] = MFMA(aq[kg], bk, s4[cc]);
        }
      }
#pragma unroll
      for (int r = 0; r < 4; r++) {
        const int q = q0 + lq * 4 + r;
        float v[4];
        float mx = NEG_BIG;
#pragma unroll
        for (int cc = 0; cc < 4; cc++) {
          v[cc] = (kbk + cc * 16 + lr > q) ? NEG_BIG : s4[cc][r];
          mx = fmaxf(mx, v[cc]);
        }
#pragma unroll
        for (int off = 8; off >= 1; off >>= 1)
          mx = fmaxf(mx, __shfl_xor(mx, off, 16));
        const float mn = fmaxf(mrow[r], mx);
        const float alpha = __expf(mrow[r] - mn);
        float sm = 0.0f;
        float p[4];
#pragma unroll
        for (int cc = 0; cc < 4; cc++) {
          p[cc] = __expf(v[cc] - mn);
          sm += p[cc];
        }
#pragma unroll
        for (int off = 8; off >= 1; off >>= 1) sm += __shfl_xor(sm, off, 16);
        lrow[r] = lrow[r] * alpha + sm;
        mrow[r] = mn;
#pragma unroll
        for (int dt = 0; dt < 4; dt++) o[dt][r] *= alpha;
#pragma unroll
        for (int cc = 0; cc < 4; cc++)
          Ps[wid][lq * 4 + r][cc * 16 + lr] = f2bf(p[cc]);
      }
      __threadfence_block();
      bfrag pf0 = ldfrag(&Ps[wid][lr][lq * 8]);
      bfrag pf1 = ldfrag(&Ps[wid][lr][32 + lq * 8]);
#pragma unroll
      for (int dt = 0; dt < 4; dt++) {
        bfrag v0 = ldfrag(&Vt[dt * 16 + lr][lq * 8]);
        bfrag v1 = ldfrag(&Vt[dt * 16 + lr][32 + lq * 8]);
        o[dt] = MFMA(pf0, v0, o[dt]);
        o[dt] = MFMA(pf1, v1, o[dt]);
      }
    }
  }

  if (qt < 4) {
    // final: normalize and write bf16
#pragma unroll
    for (int r = 0; r < 4; r++) {
      const float inv = 1.0f / fmaxf(lrow[r], 1e-30f);
      const int q = q0 + lq * 4 + r;
#pragma unroll
      for (int dt = 0; dt < 4; dt++)
        O[base + (size_t)q * 768 + dt * 16 + lr] = f2bf(o[dt][r] * inv);
    }
  } else {
    // partial: slot s = bh*140 + off(qt) + c
    int off = 0;
    for (int j = 4; j < qt; ++j) off += j / 4 + 1;
    const int s = bh * 140 + off + c;
    u16* Op = (s < 3072) ? Pn + (size_t)s * 4096
                         : Ph + (size_t)(s - 3072) * 4096;
    float* lmp = Lm + (size_t)s * 128;
#pragma unroll
    for (int r = 0; r < 4; r++) {
      const int row = wid * 16 + lq * 4 + r;
#pragma unroll
      for (int dt = 0; dt < 4; dt++)
        Op[(size_t)row * 64 + dt * 16 + lr] = f2h(o[dt][r]);
      if (lr == 0) { lmp[row] = mrow[r]; lmp[64 + row] = lrow[r]; }
    }
  }
}

// ---------------------------------------------------------------------------
// Merge partials for qt in [4,32): O = sum_c exp(m_c-m_g)*O_c / l_g.
// grid (28, 24): x = qt-4, y = bh. fp16 O partials, fp32 m/l.
// ---------------------------------------------------------------------------
__global__ __launch_bounds__(256) void attn_merge_k(
    const u16* __restrict__ Pn, const u16* __restrict__ Ph,
    const float* __restrict__ Lm, u16* __restrict__ O) {
  const int qt = 4 + blockIdx.x;
  const int bh = blockIdx.y;
  const int b = bh / 12, h = bh % 12;
  const int nc = qt / 4 + 1;
  int off = 0;
  for (int j = 4; j < qt; ++j) off += j / 4 + 1;
  const int s0 = bh * 140 + off;
  const int row = threadIdx.x >> 2;
  const int c0 = (threadIdx.x & 3) * 16;

  float mg = NEG_BIG;
  for (int cc = 0; cc < nc; ++cc)
    mg = fmaxf(mg, Lm[(size_t)(s0 + cc) * 128 + row]);

  float acc[16];
#pragma unroll
  for (int j = 0; j < 16; j++) acc[j] = 0.0f;
  float lg = 0.0f;
  for (int cc = 0; cc < nc; ++cc) {
    const int s = s0 + cc;
    const float mcv = Lm[(size_t)s * 128 + row];
    const float coef = __expf(mcv - mg);
    lg += coef * Lm[(size_t)s * 128 + 64 + row];
    const u16* Op = (s < 3072) ? Pn + (size_t)s * 4096
                               : Ph + (size_t)(s - 3072) * 4096;
    const u16* rp = Op + (size_t)row * 64 + c0;
    u16 tv[16];
    __builtin_memcpy(tv, rp, 32);
#pragma unroll
    for (int j = 0; j < 16; j++) acc[j] += coef * h2f(tv[j]);
  }
  const float inv = 1.0f / fmaxf(lg, 1e-30f);
  const int q = qt * 64 + row;
  const size_t ob = (size_t)b * 2048 * 768 + h * 64 + (size_t)q * 768 + c0;
#pragma unroll
  for (int j = 0; j < 16; j++) O[ob + j] = f2bf(acc[j] * inv);
}

// ---------------------------------------------------------------------------
extern "C" void kernel_launch(void* const* d_in, const int* in_sizes, int n_in,
                              void* d_out, int out_size, void* d_ws,
                              size_t ws_size, hipStream_t stream) {
  (void)in_sizes; (void)n_in; (void)out_size; (void)ws_size;
  const float* x = (const float*)d_in[0];
  const void* mask = d_in[2];

  char* ws = (char*)d_ws;
  u16* Wb  = (u16*)(ws);                        // bf16 arena, 23599104 B
  u16* n1h = (u16*)(ws + 23599104);             // 4096x3072 bf16 (h1 / attn partials)
  u16* Qb  = (u16*)(ws + 48764928);             // 4096x768 (later n2)
  u16* Kb2 = (u16*)(ws + 55056384);             // 4096x768
  u16* Vb2 = (u16*)(ws + 61347840);             // 4096x768
  u16* att = (u16*)(ws + 67639296);             // 4096x768 att, later ht (x1536)
  u16* hs  = (u16*)(ws + 80222208);             // 4096x1536 (attn partial spill)
  float* mfl = (float*)(ws + 92805120);         // 768 floats
  float* x1 = (float*)d_out;                    // x / x1 fp32 live in d_out
  u16* Pn16 = n1h;                              // fp16 O-partials, slots 0..3071
  u16* Ph16 = hs;                               // fp16 O-partials, slots 3072..3359
  float* Lm = (float*)(ws + 80222208 + 4194304); // m/l: 3360 slots x 128 f32

  u16* Wq = Wb + 0,        *Wk = Wb + 589824,   *Wv = Wb + 1179648;
  u16* Wo = Wb + 1769472,  *w1 = Wb + 2359296,  *w1t = Wb + 4718592;
  u16* w1s = Wb + 5898240, *w2 = Wb + 7077888,  *w2t = Wb + 9437184;
  u16* w2s = Wb + 10616832;
  u16* n1w = Wb + 11796480, *n1b = Wb + 11797248;
  u16* n2w = Wb + 11798016, *n2b = Wb + 11798784;

  Segs sg;
  const int srcidx[14] = {3, 4, 5, 6, 7, 9, 11, 8, 10, 12, 13, 14, 15, 16};
  const int offs[14] = {0, 589824, 1179648, 1769472, 2359296, 4718592,
                        5898240, 7077888, 9437184, 10616832,
                        11796480, 11797248, 11798016, 11798784};
  const int ns[14] = {589824, 589824, 589824, 589824, 2359296, 1179648,
                      1179648, 2359296, 1179648, 1179648, 768, 768, 768, 768};
  const int mms[14] = {0, 0, 0, 0, 0, 1, 2, 0, 0, 0, 0, 0, 0, 0};
  for (int i = 0; i < 14; i++) {
    sg.src[i] = d_in[srcidx[i]];
    sg.off[i] = offs[i];
    sg.n[i] = ns[i];
    sg.mmode[i] = mms[i];
  }

  mask_conv_k<<<1, 256, 0, stream>>>(mask, mfl);
  convert_k<<<dim3(2304, 14), 256, 0, stream>>>(sg, Wb, mfl);

  // n1 = mink_norm(x); also seed d_out with x (residual base for Wo atomics)
  mink_norm_k<<<4096, 256, 0, stream>>>(x, mfl, n1w, n1b, n1h, x1);

  // Q,K,V fused (N=2304), XCD-swizzled, 1-barrier loop. seg0: fused qcorr.
  GArgs qkv;
  qkv.s[0] = {Wq, Qb, 768, 6, 1};
  qkv.s[1] = {Wk, Kb2, 768, 6, 0};
  qkv.s[2] = {Wv, Vb2, 768, 6, 0};
  gemm128_fused<3><<<dim3(18, 32), 256, 0, stream>>>(n1h, 768, 768, qkv, mfl);

  // flash attention: 144 chunks/bh (chunk=4 kv-tiles), fp16 partials, merge
  flash_attn_k<<<dim3(144, 24), 256, 0, stream>>>(Qb, Kb2, Vb2, att,
                                                  Pn16, Ph16, Lm);
  attn_merge_k<<<dim3(28, 24), 256, 0, stream>>>(Pn16, Ph16, Lm, att);

  // x1 = x + att @ Wo^T  (split-K x2 atomic, 1-barrier loop)
  gemm128_wo_splitk<<<dim3(6, 32, 2), 256, 0, stream>>>(att, Wo, x1);

  // n2 = mink_norm(x1) -> Qb (mask folded into FFN1 weights)
  mink_norm_k<<<4096, 256, 0, stream>>>(x1, mfl, n2w, n2b, Qb, nullptr);

  // FFN1 fused (N=6144), 2-barrier loop (keeps 5 blocks/CU occupancy)
  GArgs ffn1;
  ffn1.s[0] = {w1, n1h, 3072, 24, 2};
  ffn1.s[1] = {w1t, att, 1536, 12, 3};
  ffn1.s[2] = {w1s, hs, 1536, 12, 2};
  gemm128_fused<2><<<dim3(48, 32), 256, 0, stream>>>(Qb, 768, 768, ffn1, mfl);

  // out = x1 + 0.5*(h1@w2^T + ht@w2_t^T + hs@w2_s^T), x4 atomic, 1-barrier
  ffn2_splitk<<<dim3(6, 32, 4), 256, 0, stream>>>(n1h, att, hs, w2, w2t, w2s,
                                                  (float*)d_out);
}

// Round 14
// 416.953 us; speedup vs baseline: 1.0021x; 1.0021x over previous
//
#include <hip/hip_runtime.h>

// LorentzBlock: B=2, L=2048, D=768, H=12, DH=64, DFF=3072
// R24: per-kernel best-config recombination. R23 A/B showed: 1-barrier
// depth-3 loop helps ffn2 (87.2->84.0, clean 3/CU steady state) but hurts
// QKV/Wo (~10us, partially-resident grids suffer the longer prologue).
// -> ffn2: NB=3 1-barrier; QKV/FFN1: NB=2 2-barrier; Wo: NB=2 2-barrier.
// Everything else = R22 (411.3us): flash chunk-4 fp16 partials, qcorr-fused
// QKV, XCD swizzle, ffn2 x4 / Wo x2 128^2 splits.

typedef unsigned short u16;
typedef __bf16 bfrag __attribute__((ext_vector_type(8)));
typedef float f32x4 __attribute__((ext_vector_type(4)));

#define MFMA(a, b, c) __builtin_amdgcn_mfma_f32_16x16x32_bf16(a, b, c, 0, 0, 0)
#define NEG_BIG (-30000.0f)
#define ASYNC16(g, l)                                                        \
  __builtin_amdgcn_global_load_lds(                                          \
      (const __attribute__((address_space(1))) unsigned int*)(g),            \
      (__attribute__((address_space(3))) unsigned int*)(l), 16, 0, 0)

__device__ __forceinline__ float bf2f(u16 u) {
  unsigned int v = ((unsigned int)u) << 16;
  float f; __builtin_memcpy(&f, &v, 4); return f;
}
__device__ __forceinline__ u16 f2bf(float f) {
  unsigned int v; __builtin_memcpy(&v, &f, 4);
  v += 0x7fffu + ((v >> 16) & 1u);   // RNE
  return (u16)(v >> 16);
}
__device__ __forceinline__ u16 f2h(float f) {
  _Float16 h = (_Float16)f; u16 u; __builtin_memcpy(&u, &h, 2); return u;
}
__device__ __forceinline__ float h2f(u16 u) {
  _Float16 h; __builtin_memcpy(&h, &u, 2); return (float)h;
}
__device__ __forceinline__ bfrag ldfrag(const u16* p) {
  bfrag v; __builtin_memcpy(&v, p, 16); return v;
}

// XCD-chunked bijective swizzle of the linear workgroup id. Requires
// nwg % 8 == 0 (all call sites comply); identity fallback otherwise.
__device__ __forceinline__ int xcd_work_id() {
  const int nx = gridDim.x, ny = gridDim.y;
  const int nwg = nx * ny * gridDim.z;
  const int orig = blockIdx.x + nx * (blockIdx.y + ny * blockIdx.z);
  if (nwg & 7) return orig;
  return (orig & 7) * (nwg >> 3) + (orig >> 3);
}

// ---------------------------------------------------------------------------
// Mask canonicalization -> float[768].
// ---------------------------------------------------------------------------
__global__ __launch_bounds__(256) void mask_conv_k(const void* __restrict__ mask,
                                                   float* __restrict__ mfl) {
  __shared__ int msh;
  if (threadIdx.x == 0) msh = 0;
  __syncthreads();
  const unsigned int* w = (const unsigned int*)mask;
  if (threadIdx.x < 192) {
    const unsigned int v = w[threadIdx.x];
    if ((v & 0xFFFFu) == 0x3F80u) atomicOr(&msh, 4);
    else if (v == 0x3F800000u) atomicOr(&msh, 2);
    else if (v >= 2u) atomicOr(&msh, 1);
  }
  __syncthreads();
  const int m = msh;
  const int mode = (m & 4) ? 3 : (m & 2) ? 2 : (m & 1) ? 1 : 0;
  for (int i = threadIdx.x; i < 768; i += 256) {
    int b;
    if (mode == 3) b = ((const u16*)mask)[i] != 0;
    else if (mode == 2) b = ((const float*)mask)[i] != 0.0f;
    else if (mode == 1) b = ((const unsigned char*)mask)[i] != 0;
    else b = ((const int*)mask)[i] != 0;
    mfl[i] = (float)b;
  }
}

// ---------------------------------------------------------------------------
// Convert fp32 weight segments -> bf16 arena. mmode: 0 none, 1 *m[k],
// 2 *(1-m[k]) with k = i % 768 (mask fold for w1_t / w1_s).
// ---------------------------------------------------------------------------
struct Segs {
  const void* src[14];
  int off[14];
  int n[14];
  int mmode[14];
};

__global__ __launch_bounds__(256) void convert_k(Segs segs, u16* __restrict__ dstb,
                                                 const float* __restrict__ mfl) {
  const int seg = blockIdx.y;
  const int n = segs.n[seg];
  const int mm = segs.mmode[seg];
  u16* dst = dstb + segs.off[seg];
  const float* src = (const float*)segs.src[seg];
  for (int i = (blockIdx.x * 256 + threadIdx.x) * 4; i < n; i += gridDim.x * 1024) {
    float4 v;
    __builtin_memcpy(&v, src + i, 16);
    if (mm) {
      const int k = i % 768;
      float m0 = mfl[k], m1 = mfl[k + 1], m2 = mfl[k + 2], m3 = mfl[k + 3];
      if (mm == 2) { m0 = 1.f - m0; m1 = 1.f - m1; m2 = 1.f - m2; m3 = 1.f - m3; }
      v.x *= m0; v.y *= m1; v.z *= m2; v.w *= m3;
    }
    dst[i] = f2bf(v.x); dst[i + 1] = f2bf(v.y);
    dst[i + 2] = f2bf(v.z); dst[i + 3] = f2bf(v.w);
  }
}

// ---------------------------------------------------------------------------
// Minkowski LayerNorm. fp32 input, bf16 output. Optionally copies the raw
// input row to Xcopy (fp32) -- seeds d_out with x for the Wo split-K atomics.
// ---------------------------------------------------------------------------
__global__ __launch_bounds__(256) void mink_norm_k(
    const float* __restrict__ X, const float* __restrict__ mf,
    const u16* __restrict__ w, const u16* __restrict__ bias,
    u16* __restrict__ Y, float* __restrict__ Xcopy) {
  __shared__ float red[8];
  const int row = blockIdx.x, tid = threadIdx.x;
  const int wid = tid >> 6, lane = tid & 63;
  const size_t roff = (size_t)row * 768;

  float xv[3], mv[3];
  int idx[3];
#pragma unroll
  for (int i = 0; i < 3; i++) {
    idx[i] = tid + i * 256;
    xv[i] = X[roff + idx[i]];
    mv[i] = mf[idx[i]];
  }
  if (Xcopy) {
#pragma unroll
    for (int i = 0; i < 3; i++) Xcopy[roff + idx[i]] = xv[i];
  }
  float s = xv[0] + xv[1] + xv[2];
#pragma unroll
  for (int o = 32; o >= 1; o >>= 1) s += __shfl_xor(s, o, 64);
  if (lane == 0) red[wid] = s;
  __syncthreads();
  const float mean = (red[0] + red[1] + red[2] + red[3]) * (1.0f / 768.0f);
  __syncthreads();

  float xc[3], ss = 0.0f, sm = 0.0f;
#pragma unroll
  for (int i = 0; i < 3; i++) {
    xc[i] = xv[i] - mean;
    ss += xc[i] * xc[i];
    sm += xc[i] * xc[i] * mv[i];
  }
#pragma unroll
  for (int o = 32; o >= 1; o >>= 1) {
    ss += __shfl_xor(ss, o, 64);
    sm += __shfl_xor(sm, o, 64);
  }
  if (lane == 0) { red[wid] = ss; red[4 + wid] = sm; }
  __syncthreads();
  const float sumsq = red[0] + red[1] + red[2] + red[3];
  const float summ = red[4] + red[5] + red[6] + red[7];
  const float var = sumsq * (1.0f / 768.0f);
  const float eta = sumsq - 2.0f * summ;
  const float rs = 1.0f / sqrtf(var + 1e-5f);
  const float re = 1.0f / sqrtf(fabsf(eta) + 1e-5f);

#pragma unroll
  for (int i = 0; i < 3; i++) {
    const float xn = xc[i] * 0.5f * (rs + re);
    Y[roff + idx[i]] = f2bf(bf2f(w[idx[i]]) * xn + bf2f(bias[idx[i]]));
  }
}

// ---------------------------------------------------------------------------
// 128x128 MFMA GEMM core, templated on LDS buffer count NB:
//  NB==2: 2-barrier depth-2 counted-vmcnt loop (32KB) -- QKV/FFN1/Wo.
//  NB==3: 1-barrier depth-3, stage-at-end (48KB) -- ffn2 only (3/CU
//  steady state; R23 A/B: helps ffn2, hurts partially-resident grids).
// ---------------------------------------------------------------------------
template <int NB>
__device__ __forceinline__ void gemm128_loop(
    const u16* __restrict__ Ab, const u16* __restrict__ Wb2,
    int K, int lda, int ldb, u16 (*As)[32], u16 (*Bs)[32], f32x4 acc[4][4]) {
  const int tid = threadIdx.x;
  const int wid = tid >> 6, lane = tid & 63;
  const int lr = lane & 15, lq = lane >> 4;
  const int srow = wid * 32 + (lane >> 2);
  const int scol = (lane & 3) * 8;
  const u16* ga0 = Ab + (size_t)srow * lda + scol;
  const u16* ga1 = Ab + (size_t)(srow + 16) * lda + scol;
  const u16* gb0 = Wb2 + (size_t)srow * ldb + scol;
  const u16* gb1 = Wb2 + (size_t)(srow + 16) * ldb + scol;
  const int wr = (wid >> 1) * 64, wc = (wid & 1) * 64;
  const int nt = K >> 5;

#define STAGE16(dbuf, k0)                                                    \
  {                                                                          \
    u16* _a0 = &As[(dbuf) * 128 + wid * 32][0];                              \
    u16* _a1 = &As[(dbuf) * 128 + wid * 32 + 16][0];                         \
    u16* _b0 = &Bs[(dbuf) * 128 + wid * 32][0];                              \
    u16* _b1 = &Bs[(dbuf) * 128 + wid * 32 + 16][0];                         \
    ASYNC16(ga0 + (k0), _a0);                                                \
    ASYNC16(ga1 + (k0), _a1);                                                \
    ASYNC16(gb0 + (k0), _b0);                                                \
    ASYNC16(gb1 + (k0), _b1);                                                \
  }

  if constexpr (NB == 2) {
    STAGE16(0, 0);
    for (int t = 0; t < nt; ++t) {
      const int cur = t & 1;
      if (t + 1 < nt) {
        STAGE16(cur ^ 1, (t + 1) << 5);
        __builtin_amdgcn_sched_barrier(0);
        asm volatile("s_waitcnt vmcnt(4)" ::: "memory");
      } else {
        asm volatile("s_waitcnt vmcnt(0)" ::: "memory");
      }
      __builtin_amdgcn_s_barrier();
      __builtin_amdgcn_sched_barrier(0);
      bfrag af[4], bf4[4];
#pragma unroll
      for (int i = 0; i < 4; i++)
        af[i] = ldfrag(&As[cur * 128 + wr + i * 16 + lr][lq * 8]);
#pragma unroll
      for (int j = 0; j < 4; j++)
        bf4[j] = ldfrag(&Bs[cur * 128 + wc + j * 16 + lr][lq * 8]);
#pragma unroll
      for (int i = 0; i < 4; i++)
#pragma unroll
        for (int j = 0; j < 4; j++)
          acc[i][j] = MFMA(af[i], bf4[j], acc[i][j]);
      asm volatile("s_waitcnt lgkmcnt(0)" ::: "memory");
      __builtin_amdgcn_sched_barrier(0);
      __builtin_amdgcn_s_barrier();
    }
  } else {
    // 1-barrier depth-3, stage-at-end
    STAGE16(0, 0);
    if (nt > 1) STAGE16(1, 32);
    for (int t = 0; t < nt; ++t) {
      const int cur = t % 3;
      if (t + 1 < nt)
        asm volatile("s_waitcnt vmcnt(4)" ::: "memory");
      else
        asm volatile("s_waitcnt vmcnt(0)" ::: "memory");
      __builtin_amdgcn_s_barrier();
      __builtin_amdgcn_sched_barrier(0);
      bfrag af[4], bf4[4];
#pragma unroll
      for (int i = 0; i < 4; i++)
        af[i] = ldfrag(&As[cur * 128 + wr + i * 16 + lr][lq * 8]);
#pragma unroll
      for (int j = 0; j < 4; j++)
        bf4[j] = ldfrag(&Bs[cur * 128 + wc + j * 16 + lr][lq * 8]);
#pragma unroll
      for (int i = 0; i < 4; i++)
#pragma unroll
        for (int j = 0; j < 4; j++)
          acc[i][j] = MFMA(af[i], bf4[j], acc[i][j]);
      __builtin_amdgcn_sched_barrier(0);
      if (t + 2 < nt) STAGE16((t + 2) % 3, (t + 2) << 5);
    }
  }
#undef STAGE16
}

// ---------------------------------------------------------------------------
// Fused multi-segment GEMM, bf16 out: C_seg = epi(A @ Wseg^T).
// epi: 0 none, 1 Lorentz-Q correction (fused qcorr), 2 gelu, 3 silu.
// NB==2 (QKV & FFN1 both use the 2-barrier loop).
// ---------------------------------------------------------------------------
struct GSeg { const u16* W; u16* C; int ldc; int nblk; int epi; };
struct GArgs { GSeg s[3]; };

__global__ __launch_bounds__(256) void gemm128_fused(
    const u16* __restrict__ A, int lda, int K, GArgs args,
    const float* __restrict__ mfl) {
  __shared__ __align__(16) u16 As[256][32];
  __shared__ __align__(16) u16 Bs[256][32];
  const int w = xcd_work_id();
  int cb = w % gridDim.x, seg = 0;
  const int by = w / gridDim.x;
  while (cb >= args.s[seg].nblk) { cb -= args.s[seg].nblk; seg++; }
  const GSeg g = args.s[seg];
  const int rowb = by * 128, colb = cb * 128;
  f32x4 acc[4][4] = {};
  gemm128_loop<2>(A + (size_t)rowb * lda, g.W + (size_t)colb * K, K, lda, K,
                  As, Bs, acc);

  const int lane = threadIdx.x & 63, wid = threadIdx.x >> 6;
  const int lr = lane & 15, lq = lane >> 4;
  const int wr = (wid >> 1) * 64, wc = (wid & 1) * 64;

  if (g.epi == 1) {
    // fused Lorentz Q correction (head-aligned 64-col block per wave)
    const int cb64 = colb + wc;
    float mj[4];
#pragma unroll
    for (int j = 0; j < 4; j++) mj[j] = mfl[cb64 + j * 16 + lr];
#pragma unroll
    for (int i = 0; i < 4; i++)
#pragma unroll
      for (int r = 0; r < 4; r++) {
        float p2 = 0.0f, pm2 = 0.0f;
#pragma unroll
        for (int j = 0; j < 4; j++) {
          const float v = acc[i][j][r];
          p2 += v * v;
          pm2 += v * v * mj[j];
        }
#pragma unroll
        for (int off = 8; off >= 1; off >>= 1) {
          p2 += __shfl_xor(p2, off, 64);
          pm2 += __shfl_xor(pm2, off, 64);
        }
        const float qn = sqrtf(p2), qtn = sqrtf(pm2);
        const float sf = (qtn > 1e-6f) ? qn / fmaxf(qtn, 1e-8f) : 0.0f;
        const int row = rowb + wr + i * 16 + lq * 4 + r;
#pragma unroll
        for (int j = 0; j < 4; j++) {
          const int col = cb64 + j * 16 + lr;
          const float v = acc[i][j][r] * (1.0f - 0.5f * sf * mj[j]) * 0.125f;
          g.C[(size_t)row * g.ldc + col] = f2bf(v);
        }
      }
    return;
  }

#pragma unroll
  for (int i = 0; i < 4; i++)
#pragma unroll
    for (int j = 0; j < 4; j++)
#pragma unroll
      for (int r = 0; r < 4; r++) {
        const int row = rowb + wr + i * 16 + lq * 4 + r;
        const int col = colb + wc + j * 16 + lr;
        float v = acc[i][j][r];
        if (g.epi == 2) v = 0.5f * v * (1.0f + erff(v * 0.70710678118654752f));
        else if (g.epi == 3) v = v / (1.0f + __expf(-v));
        g.C[(size_t)row * g.ldc + col] = f2bf(v);
      }
}

// ---------------------------------------------------------------------------
// Wo projection split-K x2 (128^2 tiles, 2-barrier loop): Out += att@Wo^T.
// Out (d_out) holds x. grid (6,32,2), XCD-swizzled.
// ---------------------------------------------------------------------------
__global__ __launch_bounds__(256) void gemm128_wo_splitk(
    const u16* __restrict__ A, const u16* __restrict__ W,
    float* __restrict__ Out) {
  __shared__ __align__(16) u16 As[256][32];
  __shared__ __align__(16) u16 Bs[256][32];
  const int w = xcd_work_id();
  const int bx = w % gridDim.x;
  const int by = (w / gridDim.x) % gridDim.y;
  const int z = w / (gridDim.x * gridDim.y);
  const int rowb = by * 128, colb = bx * 128;
  f32x4 acc[4][4] = {};
  gemm128_loop<2>(A + (size_t)rowb * 768 + z * 384,
                  W + (size_t)colb * 768 + z * 384, 384, 768, 768,
                  As, Bs, acc);

  const int lane = threadIdx.x & 63, wid = threadIdx.x >> 6;
  const int lr = lane & 15, lq = lane >> 4;
  const int wr = (wid >> 1) * 64, wc = (wid & 1) * 64;
#pragma unroll
  for (int i = 0; i < 4; i++)
#pragma unroll
    for (int j = 0; j < 4; j++)
#pragma unroll
      for (int r = 0; r < 4; r++) {
        const int row = rowb + wr + i * 16 + lq * 4 + r;
        const int col = colb + wc + j * 16 + lr;
        atomicAdd(&Out[(size_t)row * 768 + col], acc[i][j][r]);
      }
}

// ---------------------------------------------------------------------------
// FFN2 split-K x4 (128^2 tiles, 1-barrier depth-3 loop): Out += 0.5*partial.
// Out holds x1. grid (6,32,4), XCD-swizzled. (R23 A/B: 84.0 vs 87.2us.)
// ---------------------------------------------------------------------------
__global__ __launch_bounds__(256) void ffn2_splitk(
    const u16* __restrict__ H1, const u16* __restrict__ Ht,
    const u16* __restrict__ Hs, const u16* __restrict__ W2,
    const u16* __restrict__ W2t, const u16* __restrict__ W2s,
    float* __restrict__ Out) {
  __shared__ __align__(16) u16 As[384][32];
  __shared__ __align__(16) u16 Bs[384][32];
  const int w = xcd_work_id();
  const int bx = w % gridDim.x;
  const int by = (w / gridDim.x) % gridDim.y;
  const int z = w / (gridDim.x * gridDim.y);
  const int rowb = by * 128, colb = bx * 128;
  f32x4 acc[4][4] = {};
  if (z == 0)
    gemm128_loop<3>(H1 + (size_t)rowb * 3072, W2 + (size_t)colb * 3072,
                    1536, 3072, 3072, As, Bs, acc);
  else if (z == 1)
    gemm128_loop<3>(H1 + (size_t)rowb * 3072 + 1536,
                    W2 + (size_t)colb * 3072 + 1536,
                    1536, 3072, 3072, As, Bs, acc);
  else if (z == 2)
    gemm128_loop<3>(Ht + (size_t)rowb * 1536, W2t + (size_t)colb * 1536,
                    1536, 1536, 1536, As, Bs, acc);
  else
    gemm128_loop<3>(Hs + (size_t)rowb * 1536, W2s + (size_t)colb * 1536,
                    1536, 1536, 1536, As, Bs, acc);

  const int lane = threadIdx.x & 63, wid = threadIdx.x >> 6;
  const int lr = lane & 15, lq = lane >> 4;
  const int wr = (wid >> 1) * 64, wc = (wid & 1) * 64;
#pragma unroll
  for (int i = 0; i < 4; i++)
#pragma unroll
    for (int j = 0; j < 4; j++)
#pragma unroll
      for (int r = 0; r < 4; r++) {
        const int row = rowb + wr + i * 16 + lq * 4 + r;
        const int col = colb + wc + j * 16 + lr;
        atomicAdd(&Out[(size_t)row * 768 + col], 0.5f * acc[i][j][r]);
      }
}

// ---------------------------------------------------------------------------
// Flash attention producer, causal, KV-split chunk=4 (R22). QBLK=64, 4 waves.
// Per bh: 144 blocks. qt<4: writes final bf16. qt>=4: fp16 O partial +
// fp32 (m,l) at slot s = bh*140 + off(qt) + c.
// ---------------------------------------------------------------------------
__global__ __launch_bounds__(256) void flash_attn_k(
    const u16* __restrict__ Qc, const u16* __restrict__ Kb,
    const u16* __restrict__ Vb, u16* __restrict__ O,
    u16* __restrict__ Pn, u16* __restrict__ Ph, float* __restrict__ Lm) {
  __shared__ __align__(16) u16 Ks[64][40];
  __shared__ __align__(16) u16 Vt[64][72];
  __shared__ __align__(16) u16 Ps[4][16][72];
  const int tid = threadIdx.x, wid = tid >> 6, lane = tid & 63;
  const int lr = lane & 15, lq = lane >> 4;

  // decode blockIdx.x -> (qt, c); qt descending so long chunks launch first
  int bx = blockIdx.x, qt = 0, c = 0;
  for (int q = 31; q >= 0; --q) {
    const int nc = (q < 4) ? 1 : (q / 4 + 1);
    if (bx < nc) { qt = q; c = bx; break; }
    bx -= nc;
  }
  const int nt = qt + 1;
  const int t0 = c * 4;
  const int t1 = (t0 + 4 < nt) ? t0 + 4 : nt;

  const int qb = qt * 64;
  const int bh = blockIdx.y;
  const int b = bh / 12, h = bh % 12;
  const int q0 = qb + wid * 16;
  const size_t base = (size_t)b * 2048 * 768 + h * 64;

  bfrag aq[2];
  aq[0] = ldfrag(Qc + base + (size_t)(q0 + lr) * 768 + lq * 8);
  aq[1] = ldfrag(Qc + base + (size_t)(q0 + lr) * 768 + 32 + lq * 8);

  f32x4 o[4] = {};
  float mrow[4] = {NEG_BIG, NEG_BIG, NEG_BIG, NEG_BIG};
  float lrow[4] = {0.0f, 0.0f, 0.0f, 0.0f};

  const int krow = tid >> 3;        // 0..31
  const int kcol = (tid & 7) * 8;
  const int vkey = tid & 31;
  const int vdg = tid >> 5;         // 0..7

  const u16* kp = Kb + base + (size_t)(t0 * 64 + krow) * 768 + kcol;
  const u16* vp = Vb + base + (size_t)(t0 * 64 + vkey) * 768 + vdg * 8;

  uint4 kv0, kv1, vv0, vv1;
  __builtin_memcpy(&kv0, kp, 16);
  __builtin_memcpy(&kv1, kp + (size_t)32 * 768, 16);
  __builtin_memcpy(&vv0, vp, 16);
  __builtin_memcpy(&vv1, vp + (size_t)32 * 768, 16);

  for (int kt = t0; kt < t1; kt++) {
    __syncthreads();
    __builtin_memcpy(&Ks[krow][kcol], &kv0, 16);
    __builtin_memcpy(&Ks[krow + 32][kcol], &kv1, 16);
    {
      union { uint4 u; u16 s[8]; } a, b2;
      a.u = vv0; b2.u = vv1;
#pragma unroll
      for (int j = 0; j < 8; j++) {
        Vt[vdg * 8 + j][vkey] = a.s[j];
        Vt[vdg * 8 + j][vkey + 32] = b2.s[j];
      }
    }
    __syncthreads();
    if (kt + 1 < t1) {
      const size_t koff = (size_t)(kt + 1 - t0) * 64 * 768;
      __builtin_memcpy(&kv0, kp + koff, 16);
      __builtin_memcpy(&kv1, kp + koff + (size_t)32 * 768, 16);
      __builtin_memcpy(&vv0, vp + koff, 16);
      __builtin_memcpy(&vv1, vp + koff + (size_t)32 * 768, 16);
    }

    const int kbk = kt * 64;
    {
      f32x4 s4[4] = {};
#pragma unroll
      for (int kg = 0; kg < 2; kg++) {
#pragma unroll
        for (int cc = 0; cc < 4; cc++) {
          bfrag bk = ldfrag(&Ks[cc * 16 + lr][kg * 32 + lq * 8]);
          s4[cc] = MFMA(aq[kg], bk, s4[cc]);
        }
      }
#pragma unroll
      for (int r = 0; r < 4; r++) {
        const int q = q0 + lq * 4 + r;
        float v[4];
        float mx = NEG_BIG;
#pragma unroll
        for (int cc = 0; cc < 4; cc++) {
          v[cc] = (kbk + cc * 16 + lr > q) ? NEG_BIG : s4[cc][r];
          mx = fmaxf(mx, v[cc]);
        }
#pragma unroll
        for (int off = 8; off >= 1; off >>= 1)
          mx = fmaxf(mx, __shfl_xor(mx, off, 16));
        const float mn = fmaxf(mrow[r], mx);
        const float alpha = __expf(mrow[r] - mn);
        float sm = 0.0f;
        float p[4];
#pragma unroll
        for (int cc = 0; cc < 4; cc++) {
          p[cc] = __expf(v[cc] - mn);
          sm += p[cc];
        }
#pragma unroll
        for (int off = 8; off >= 1; off >>= 1) sm += __shfl_xor(sm, off, 16);
        lrow[r] = lrow[r] * alpha + sm;
        mrow[r] = mn;
#pragma unroll
        for (int dt = 0; dt < 4; dt++) o[dt][r] *= alpha;
#pragma unroll
        for (int cc = 0; cc < 4; cc++)
          Ps[wid][lq * 4 + r][cc * 16 + lr] = f2bf(p[cc]);
      }
      __threadfence_block();
      bfrag pf0 = ldfrag(&Ps[wid][lr][lq * 8]);
      bfrag pf1 = ldfrag(&Ps[wid][lr][32 + lq * 8]);
#pragma unroll
      for (int dt = 0; dt < 4; dt++) {
        bfrag v0 = ldfrag(&Vt[dt * 16 + lr][lq * 8]);
        bfrag v1 = ldfrag(&Vt[dt * 16 + lr][32 + lq * 8]);
        o[dt] = MFMA(pf0, v0, o[dt]);
        o[dt] = MFMA(pf1, v1, o[dt]);
      }
    }
  }

  if (qt < 4) {
    // final: normalize and write bf16
#pragma unroll
    for (int r = 0; r < 4; r++) {
      const float inv = 1.0f / fmaxf(lrow[r], 1e-30f);
      const int q = q0 + lq * 4 + r;
#pragma unroll
      for (int dt = 0; dt < 4; dt++)
        O[base + (size_t)q * 768 + dt * 16 + lr] = f2bf(o[dt][r] * inv);
    }
  } else {
    // partial: slot s = bh*140 + off(qt) + c
    int off = 0;
    for (int j = 4; j < qt; ++j) off += j / 4 + 1;
    const int s = bh * 140 + off + c;
    u16* Op = (s < 3072) ? Pn + (size_t)s * 4096
                         : Ph + (size_t)(s - 3072) * 4096;
    float* lmp = Lm + (size_t)s * 128;
#pragma unroll
    for (int r = 0; r < 4; r++) {
      const int row = wid * 16 + lq * 4 + r;
#pragma unroll
      for (int dt = 0; dt < 4; dt++)
        Op[(size_t)row * 64 + dt * 16 + lr] = f2h(o[dt][r]);
      if (lr == 0) { lmp[row] = mrow[r]; lmp[64 + row] = lrow[r]; }
    }
  }
}

// ---------------------------------------------------------------------------
// Merge partials for qt in [4,32): O = sum_c exp(m_c-m_g)*O_c / l_g.
// grid (28, 24): x = qt-4, y = bh. fp16 O partials, fp32 m/l.
// ---------------------------------------------------------------------------
__global__ __launch_bounds__(256) void attn_merge_k(
    const u16* __restrict__ Pn, const u16* __restrict__ Ph,
    const float* __restrict__ Lm, u16* __restrict__ O) {
  const int qt = 4 + blockIdx.x;
  const int bh = blockIdx.y;
  const int b = bh / 12, h = bh % 12;
  const int nc = qt / 4 + 1;
  int off = 0;
  for (int j = 4; j < qt; ++j) off += j / 4 + 1;
  const int s0 = bh * 140 + off;
  const int row = threadIdx.x >> 2;
  const int c0 = (threadIdx.x & 3) * 16;

  float mg = NEG_BIG;
  for (int cc = 0; cc < nc; ++cc)
    mg = fmaxf(mg, Lm[(size_t)(s0 + cc) * 128 + row]);

  float acc[16];
#pragma unroll
  for (int j = 0; j < 16; j++) acc[j] = 0.0f;
  float lg = 0.0f;
  for (int cc = 0; cc < nc; ++cc) {
    const int s = s0 + cc;
    const float mcv = Lm[(size_t)s * 128 + row];
    const float coef = __expf(mcv - mg);
    lg += coef * Lm[(size_t)s * 128 + 64 + row];
    const u16* Op = (s < 3072) ? Pn + (size_t)s * 4096
                               : Ph + (size_t)(s - 3072) * 4096;
    const u16* rp = Op + (size_t)row * 64 + c0;
    u16 tv[16];
    __builtin_memcpy(tv, rp, 32);
#pragma unroll
    for (int j = 0; j < 16; j++) acc[j] += coef * h2f(tv[j]);
  }
  const float inv = 1.0f / fmaxf(lg, 1e-30f);
  const int q = qt * 64 + row;
  const size_t ob = (size_t)b * 2048 * 768 + h * 64 + (size_t)q * 768 + c0;
#pragma unroll
  for (int j = 0; j < 16; j++) O[ob + j] = f2bf(acc[j] * inv);
}

// ---------------------------------------------------------------------------
extern "C" void kernel_launch(void* const* d_in, const int* in_sizes, int n_in,
                              void* d_out, int out_size, void* d_ws,
                              size_t ws_size, hipStream_t stream) {
  (void)in_sizes; (void)n_in; (void)out_size; (void)ws_size;
  const float* x = (const float*)d_in[0];
  const void* mask = d_in[2];

  char* ws = (char*)d_ws;
  u16* Wb  = (u16*)(ws);                        // bf16 arena, 23599104 B
  u16* n1h = (u16*)(ws + 23599104);             // 4096x3072 bf16 (h1 / attn partials)
  u16* Qb  = (u16*)(ws + 48764928);             // 4096x768 (later n2)
  u16* Kb2 = (u16*)(ws + 55056384);             // 4096x768
  u16* Vb2 = (u16*)(ws + 61347840);             // 4096x768
  u16* att = (u16*)(ws + 67639296);             // 4096x768 att, later ht (x1536)
  u16* hs  = (u16*)(ws + 80222208);             // 4096x1536 (attn partial spill)
  float* mfl = (float*)(ws + 92805120);         // 768 floats
  float* x1 = (float*)d_out;                    // x / x1 fp32 live in d_out
  u16* Pn16 = n1h;                              // fp16 O-partials, slots 0..3071
  u16* Ph16 = hs;                               // fp16 O-partials, slots 3072..3359
  float* Lm = (float*)(ws + 80222208 + 4194304); // m/l: 3360 slots x 128 f32

  u16* Wq = Wb + 0,        *Wk = Wb + 589824,   *Wv = Wb + 1179648;
  u16* Wo = Wb + 1769472,  *w1 = Wb + 2359296,  *w1t = Wb + 4718592;
  u16* w1s = Wb + 5898240, *w2 = Wb + 7077888,  *w2t = Wb + 9437184;
  u16* w2s = Wb + 10616832;
  u16* n1w = Wb + 11796480, *n1b = Wb + 11797248;
  u16* n2w = Wb + 11798016, *n2b = Wb + 11798784;

  Segs sg;
  const int srcidx[14] = {3, 4, 5, 6, 7, 9, 11, 8, 10, 12, 13, 14, 15, 16};
  const int offs[14] = {0, 589824, 1179648, 1769472, 2359296, 4718592,
                        5898240, 7077888, 9437184, 10616832,
                        11796480, 11797248, 11798016, 11798784};
  const int ns[14] = {589824, 589824, 589824, 589824, 2359296, 1179648,
                      1179648, 2359296, 1179648, 1179648, 768, 768, 768, 768};
  const int mms[14] = {0, 0, 0, 0, 0, 1, 2, 0, 0, 0, 0, 0, 0, 0};
  for (int i = 0; i < 14; i++) {
    sg.src[i] = d_in[srcidx[i]];
    sg.off[i] = offs[i];
    sg.n[i] = ns[i];
    sg.mmode[i] = mms[i];
  }

  mask_conv_k<<<1, 256, 0, stream>>>(mask, mfl);
  convert_k<<<dim3(2304, 14), 256, 0, stream>>>(sg, Wb, mfl);

  // n1 = mink_norm(x); also seed d_out with x (residual base for Wo atomics)
  mink_norm_k<<<4096, 256, 0, stream>>>(x, mfl, n1w, n1b, n1h, x1);

  // Q,K,V fused (N=2304), XCD-swizzled, 2-barrier loop. seg0: fused qcorr.
  GArgs qkv;
  qkv.s[0] = {Wq, Qb, 768, 6, 1};
  qkv.s[1] = {Wk, Kb2, 768, 6, 0};
  qkv.s[2] = {Wv, Vb2, 768, 6, 0};
  gemm128_fused<<<dim3(18, 32), 256, 0, stream>>>(n1h, 768, 768, qkv, mfl);

  // flash attention: 144 chunks/bh (chunk=4 kv-tiles), fp16 partials, merge
  flash_attn_k<<<dim3(144, 24), 256, 0, stream>>>(Qb, Kb2, Vb2, att,
                                                  Pn16, Ph16, Lm);
  attn_merge_k<<<dim3(28, 24), 256, 0, stream>>>(Pn16, Ph16, Lm, att);

  // x1 = x + att @ Wo^T  (split-K x2 atomic, 2-barrier loop)
  gemm128_wo_splitk<<<dim3(6, 32, 2), 256, 0, stream>>>(att, Wo, x1);

  // n2 = mink_norm(x1) -> Qb (mask folded into FFN1 weights)
  mink_norm_k<<<4096, 256, 0, stream>>>(x1, mfl, n2w, n2b, Qb, nullptr);

  // FFN1 fused (N=6144), 2-barrier loop (keeps 5 blocks/CU occupancy)
  GArgs ffn1;
  ffn1.s[0] = {w1, n1h, 3072, 24, 2};
  ffn1.s[1] = {w1t, att, 1536, 12, 3};
  ffn1.s[2] = {w1s, hs, 1536, 12, 2};
  gemm128_fused<<<dim3(48, 32), 256, 0, stream>>>(Qb, 768, 768, ffn1, mfl);

  // out = x1 + 0.5*(h1@w2^T + ht@w2_t^T + hs@w2_s^T), x4 atomic, 1-barrier
  ffn2_splitk<<<dim3(6, 32, 4), 256, 0, stream>>>(n1h, att, hs, w2, w2t, w2s,
                                                  (float*)d_out);
}

// Round 15
// 412.794 us; speedup vs baseline: 1.0122x; 1.0101x over previous
//
#include <hip/hip_runtime.h>

// LorentzBlock: B=2, L=2048, D=768, H=12, DH=64, DFF=3072
// R25: (a) convert_k exact 1-D grid (11524 blocks vs 32256; 20.7k no-op
// dispatches removed); (b) T5 s_setprio(1) around MFMA cluster in the
// NB=3 ffn2 loop (1-barrier stage-at-end has wave role-split -> T5's
// paying regime per m218b; null-risk). Otherwise R24 (= per-kernel best):
// ffn2 NB=3 x4 split (84us), QKV/FFN1/Wo NB=2, flash chunk-4 fp16
// partials + merge, qcorr-fused QKV, XCD swizzle everywhere.
// Cross-run total noise measured at +/-6us (R22 411.3 vs R24 417.0 with
// strictly-better per-kernel configs) -- gains below that are unverifiable.

typedef unsigned short u16;
typedef __bf16 bfrag __attribute__((ext_vector_type(8)));
typedef float f32x4 __attribute__((ext_vector_type(4)));

#define MFMA(a, b, c) __builtin_amdgcn_mfma_f32_16x16x32_bf16(a, b, c, 0, 0, 0)
#define NEG_BIG (-30000.0f)
#define ASYNC16(g, l)                                                        \
  __builtin_amdgcn_global_load_lds(                                          \
      (const __attribute__((address_space(1))) unsigned int*)(g),            \
      (__attribute__((address_space(3))) unsigned int*)(l), 16, 0, 0)

__device__ __forceinline__ float bf2f(u16 u) {
  unsigned int v = ((unsigned int)u) << 16;
  float f; __builtin_memcpy(&f, &v, 4); return f;
}
__device__ __forceinline__ u16 f2bf(float f) {
  unsigned int v; __builtin_memcpy(&v, &f, 4);
  v += 0x7fffu + ((v >> 16) & 1u);   // RNE
  return (u16)(v >> 16);
}
__device__ __forceinline__ u16 f2h(float f) {
  _Float16 h = (_Float16)f; u16 u; __builtin_memcpy(&u, &h, 2); return u;
}
__device__ __forceinline__ float h2f(u16 u) {
  _Float16 h; __builtin_memcpy(&h, &u, 2); return (float)h;
}
__device__ __forceinline__ bfrag ldfrag(const u16* p) {
  bfrag v; __builtin_memcpy(&v, p, 16); return v;
}

// XCD-chunked bijective swizzle of the linear workgroup id. Requires
// nwg % 8 == 0 (all call sites comply); identity fallback otherwise.
__device__ __forceinline__ int xcd_work_id() {
  const int nx = gridDim.x, ny = gridDim.y;
  const int nwg = nx * ny * gridDim.z;
  const int orig = blockIdx.x + nx * (blockIdx.y + ny * blockIdx.z);
  if (nwg & 7) return orig;
  return (orig & 7) * (nwg >> 3) + (orig >> 3);
}

// ---------------------------------------------------------------------------
// Mask canonicalization -> float[768].
// ---------------------------------------------------------------------------
__global__ __launch_bounds__(256) void mask_conv_k(const void* __restrict__ mask,
                                                   float* __restrict__ mfl) {
  __shared__ int msh;
  if (threadIdx.x == 0) msh = 0;
  __syncthreads();
  const unsigned int* w = (const unsigned int*)mask;
  if (threadIdx.x < 192) {
    const unsigned int v = w[threadIdx.x];
    if ((v & 0xFFFFu) == 0x3F80u) atomicOr(&msh, 4);
    else if (v == 0x3F800000u) atomicOr(&msh, 2);
    else if (v >= 2u) atomicOr(&msh, 1);
  }
  __syncthreads();
  const int m = msh;
  const int mode = (m & 4) ? 3 : (m & 2) ? 2 : (m & 1) ? 1 : 0;
  for (int i = threadIdx.x; i < 768; i += 256) {
    int b;
    if (mode == 3) b = ((const u16*)mask)[i] != 0;
    else if (mode == 2) b = ((const float*)mask)[i] != 0.0f;
    else if (mode == 1) b = ((const unsigned char*)mask)[i] != 0;
    else b = ((const int*)mask)[i] != 0;
    mfl[i] = (float)b;
  }
}

// ---------------------------------------------------------------------------
// Convert fp32 weight segments -> bf16 arena, exact 1-D grid (R25).
// blk0[i] = first block of segment i; block handles 1024 contiguous elems.
// mmode: 0 none, 1 *m[k], 2 *(1-m[k]) with k = i % 768.
// ---------------------------------------------------------------------------
struct Segs {
  const void* src[14];
  int off[14];
  int n[14];
  int mmode[14];
  int blk0[15];
};

__global__ __launch_bounds__(256) void convert_k(Segs segs, u16* __restrict__ dstb,
                                                 const float* __restrict__ mfl) {
  int seg = 0;
  while (seg < 13 && (int)blockIdx.x >= segs.blk0[seg + 1]) seg++;
  const int local = blockIdx.x - segs.blk0[seg];
  const int n = segs.n[seg];
  const int mm = segs.mmode[seg];
  u16* dst = dstb + segs.off[seg];
  const float* src = (const float*)segs.src[seg];
  const int i = (local * 256 + threadIdx.x) * 4;
  if (i >= n) return;
  float4 v;
  __builtin_memcpy(&v, src + i, 16);
  if (mm) {
    const int k = i % 768;
    float m0 = mfl[k], m1 = mfl[k + 1], m2 = mfl[k + 2], m3 = mfl[k + 3];
    if (mm == 2) { m0 = 1.f - m0; m1 = 1.f - m1; m2 = 1.f - m2; m3 = 1.f - m3; }
    v.x *= m0; v.y *= m1; v.z *= m2; v.w *= m3;
  }
  dst[i] = f2bf(v.x); dst[i + 1] = f2bf(v.y);
  dst[i + 2] = f2bf(v.z); dst[i + 3] = f2bf(v.w);
}

// ---------------------------------------------------------------------------
// Minkowski LayerNorm. fp32 input, bf16 output. Optionally copies the raw
// input row to Xcopy (fp32) -- seeds d_out with x for the Wo split-K atomics.
// ---------------------------------------------------------------------------
__global__ __launch_bounds__(256) void mink_norm_k(
    const float* __restrict__ X, const float* __restrict__ mf,
    const u16* __restrict__ w, const u16* __restrict__ bias,
    u16* __restrict__ Y, float* __restrict__ Xcopy) {
  __shared__ float red[8];
  const int row = blockIdx.x, tid = threadIdx.x;
  const int wid = tid >> 6, lane = tid & 63;
  const size_t roff = (size_t)row * 768;

  float xv[3], mv[3];
  int idx[3];
#pragma unroll
  for (int i = 0; i < 3; i++) {
    idx[i] = tid + i * 256;
    xv[i] = X[roff + idx[i]];
    mv[i] = mf[idx[i]];
  }
  if (Xcopy) {
#pragma unroll
    for (int i = 0; i < 3; i++) Xcopy[roff + idx[i]] = xv[i];
  }
  float s = xv[0] + xv[1] + xv[2];
#pragma unroll
  for (int o = 32; o >= 1; o >>= 1) s += __shfl_xor(s, o, 64);
  if (lane == 0) red[wid] = s;
  __syncthreads();
  const float mean = (red[0] + red[1] + red[2] + red[3]) * (1.0f / 768.0f);
  __syncthreads();

  float xc[3], ss = 0.0f, sm = 0.0f;
#pragma unroll
  for (int i = 0; i < 3; i++) {
    xc[i] = xv[i] - mean;
    ss += xc[i] * xc[i];
    sm += xc[i] * xc[i] * mv[i];
  }
#pragma unroll
  for (int o = 32; o >= 1; o >>= 1) {
    ss += __shfl_xor(ss, o, 64);
    sm += __shfl_xor(sm, o, 64);
  }
  if (lane == 0) { red[wid] = ss; red[4 + wid] = sm; }
  __syncthreads();
  const float sumsq = red[0] + red[1] + red[2] + red[3];
  const float summ = red[4] + red[5] + red[6] + red[7];
  const float var = sumsq * (1.0f / 768.0f);
  const float eta = sumsq - 2.0f * summ;
  const float rs = 1.0f / sqrtf(var + 1e-5f);
  const float re = 1.0f / sqrtf(fabsf(eta) + 1e-5f);

#pragma unroll
  for (int i = 0; i < 3; i++) {
    const float xn = xc[i] * 0.5f * (rs + re);
    Y[roff + idx[i]] = f2bf(bf2f(w[idx[i]]) * xn + bf2f(bias[idx[i]]));
  }
}

// ---------------------------------------------------------------------------
// 128x128 MFMA GEMM core, templated on LDS buffer count NB:
//  NB==2: 2-barrier depth-2 counted-vmcnt loop (32KB) -- QKV/FFN1/Wo.
//  NB==3: 1-barrier depth-3, stage-at-end (48KB) + T5 setprio -- ffn2.
// ---------------------------------------------------------------------------
template <int NB>
__device__ __forceinline__ void gemm128_loop(
    const u16* __restrict__ Ab, const u16* __restrict__ Wb2,
    int K, int lda, int ldb, u16 (*As)[32], u16 (*Bs)[32], f32x4 acc[4][4]) {
  const int tid = threadIdx.x;
  const int wid = tid >> 6, lane = tid & 63;
  const int lr = lane & 15, lq = lane >> 4;
  const int srow = wid * 32 + (lane >> 2);
  const int scol = (lane & 3) * 8;
  const u16* ga0 = Ab + (size_t)srow * lda + scol;
  const u16* ga1 = Ab + (size_t)(srow + 16) * lda + scol;
  const u16* gb0 = Wb2 + (size_t)srow * ldb + scol;
  const u16* gb1 = Wb2 + (size_t)(srow + 16) * ldb + scol;
  const int wr = (wid >> 1) * 64, wc = (wid & 1) * 64;
  const int nt = K >> 5;

#define STAGE16(dbuf, k0)                                                    \
  {                                                                          \
    u16* _a0 = &As[(dbuf) * 128 + wid * 32][0];                              \
    u16* _a1 = &As[(dbuf) * 128 + wid * 32 + 16][0];                         \
    u16* _b0 = &Bs[(dbuf) * 128 + wid * 32][0];                              \
    u16* _b1 = &Bs[(dbuf) * 128 + wid * 32 + 16][0];                         \
    ASYNC16(ga0 + (k0), _a0);                                                \
    ASYNC16(ga1 + (k0), _a1);                                                \
    ASYNC16(gb0 + (k0), _b0);                                                \
    ASYNC16(gb1 + (k0), _b1);                                                \
  }

  if constexpr (NB == 2) {
    STAGE16(0, 0);
    for (int t = 0; t < nt; ++t) {
      const int cur = t & 1;
      if (t + 1 < nt) {
        STAGE16(cur ^ 1, (t + 1) << 5);
        __builtin_amdgcn_sched_barrier(0);
        asm volatile("s_waitcnt vmcnt(4)" ::: "memory");
      } else {
        asm volatile("s_waitcnt vmcnt(0)" ::: "memory");
      }
      __builtin_amdgcn_s_barrier();
      __builtin_amdgcn_sched_barrier(0);
      bfrag af[4], bf4[4];
#pragma unroll
      for (int i = 0; i < 4; i++)
        af[i] = ldfrag(&As[cur * 128 + wr + i * 16 + lr][lq * 8]);
#pragma unroll
      for (int j = 0; j < 4; j++)
        bf4[j] = ldfrag(&Bs[cur * 128 + wc + j * 16 + lr][lq * 8]);
#pragma unroll
      for (int i = 0; i < 4; i++)
#pragma unroll
        for (int j = 0; j < 4; j++)
          acc[i][j] = MFMA(af[i], bf4[j], acc[i][j]);
      asm volatile("s_waitcnt lgkmcnt(0)" ::: "memory");
      __builtin_amdgcn_sched_barrier(0);
      __builtin_amdgcn_s_barrier();
    }
  } else {
    // 1-barrier depth-3, stage-at-end, setprio around MFMA (T5)
    STAGE16(0, 0);
    if (nt > 1) STAGE16(1, 32);
    for (int t = 0; t < nt; ++t) {
      const int cur = t % 3;
      if (t + 1 < nt)
        asm volatile("s_waitcnt vmcnt(4)" ::: "memory");
      else
        asm volatile("s_waitcnt vmcnt(0)" ::: "memory");
      __builtin_amdgcn_s_barrier();
      __builtin_amdgcn_sched_barrier(0);
      __builtin_amdgcn_s_setprio(1);
      bfrag af[4], bf4[4];
#pragma unroll
      for (int i = 0; i < 4; i++)
        af[i] = ldfrag(&As[cur * 128 + wr + i * 16 + lr][lq * 8]);
#pragma unroll
      for (int j = 0; j < 4; j++)
        bf4[j] = ldfrag(&Bs[cur * 128 + wc + j * 16 + lr][lq * 8]);
#pragma unroll
      for (int i = 0; i < 4; i++)
#pragma unroll
        for (int j = 0; j < 4; j++)
          acc[i][j] = MFMA(af[i], bf4[j], acc[i][j]);
      __builtin_amdgcn_s_setprio(0);
      __builtin_amdgcn_sched_barrier(0);
      if (t + 2 < nt) STAGE16((t + 2) % 3, (t + 2) << 5);
    }
  }
#undef STAGE16
}

// ---------------------------------------------------------------------------
// Fused multi-segment GEMM, bf16 out: C_seg = epi(A @ Wseg^T).
// epi: 0 none, 1 Lorentz-Q correction (fused qcorr), 2 gelu, 3 silu.
// ---------------------------------------------------------------------------
struct GSeg { const u16* W; u16* C; int ldc; int nblk; int epi; };
struct GArgs { GSeg s[3]; };

__global__ __launch_bounds__(256) void gemm128_fused(
    const u16* __restrict__ A, int lda, int K, GArgs args,
    const float* __restrict__ mfl) {
  __shared__ __align__(16) u16 As[256][32];
  __shared__ __align__(16) u16 Bs[256][32];
  const int w = xcd_work_id();
  int cb = w % gridDim.x, seg = 0;
  const int by = w / gridDim.x;
  while (cb >= args.s[seg].nblk) { cb -= args.s[seg].nblk; seg++; }
  const GSeg g = args.s[seg];
  const int rowb = by * 128, colb = cb * 128;
  f32x4 acc[4][4] = {};
  gemm128_loop<2>(A + (size_t)rowb * lda, g.W + (size_t)colb * K, K, lda, K,
                  As, Bs, acc);

  const int lane = threadIdx.x & 63, wid = threadIdx.x >> 6;
  const int lr = lane & 15, lq = lane >> 4;
  const int wr = (wid >> 1) * 64, wc = (wid & 1) * 64;

  if (g.epi == 1) {
    // fused Lorentz Q correction (head-aligned 64-col block per wave)
    const int cb64 = colb + wc;
    float mj[4];
#pragma unroll
    for (int j = 0; j < 4; j++) mj[j] = mfl[cb64 + j * 16 + lr];
#pragma unroll
    for (int i = 0; i < 4; i++)
#pragma unroll
      for (int r = 0; r < 4; r++) {
        float p2 = 0.0f, pm2 = 0.0f;
#pragma unroll
        for (int j = 0; j < 4; j++) {
          const float v = acc[i][j][r];
          p2 += v * v;
          pm2 += v * v * mj[j];
        }
#pragma unroll
        for (int off = 8; off >= 1; off >>= 1) {
          p2 += __shfl_xor(p2, off, 64);
          pm2 += __shfl_xor(pm2, off, 64);
        }
        const float qn = sqrtf(p2), qtn = sqrtf(pm2);
        const float sf = (qtn > 1e-6f) ? qn / fmaxf(qtn, 1e-8f) : 0.0f;
        const int row = rowb + wr + i * 16 + lq * 4 + r;
#pragma unroll
        for (int j = 0; j < 4; j++) {
          const int col = cb64 + j * 16 + lr;
          const float v = acc[i][j][r] * (1.0f - 0.5f * sf * mj[j]) * 0.125f;
          g.C[(size_t)row * g.ldc + col] = f2bf(v);
        }
      }
    return;
  }

#pragma unroll
  for (int i = 0; i < 4; i++)
#pragma unroll
    for (int j = 0; j < 4; j++)
#pragma unroll
      for (int r = 0; r < 4; r++) {
        const int row = rowb + wr + i * 16 + lq * 4 + r;
        const int col = colb + wc + j * 16 + lr;
        float v = acc[i][j][r];
        if (g.epi == 2) v = 0.5f * v * (1.0f + erff(v * 0.70710678118654752f));
        else if (g.epi == 3) v = v / (1.0f + __expf(-v));
        g.C[(size_t)row * g.ldc + col] = f2bf(v);
      }
}

// ---------------------------------------------------------------------------
// Wo projection split-K x2 (128^2 tiles, 2-barrier loop): Out += att@Wo^T.
// Out (d_out) holds x. grid (6,32,2), XCD-swizzled.
// ---------------------------------------------------------------------------
__global__ __launch_bounds__(256) void gemm128_wo_splitk(
    const u16* __restrict__ A, const u16* __restrict__ W,
    float* __restrict__ Out) {
  __shared__ __align__(16) u16 As[256][32];
  __shared__ __align__(16) u16 Bs[256][32];
  const int w = xcd_work_id();
  const int bx = w % gridDim.x;
  const int by = (w / gridDim.x) % gridDim.y;
  const int z = w / (gridDim.x * gridDim.y);
  const int rowb = by * 128, colb = bx * 128;
  f32x4 acc[4][4] = {};
  gemm128_loop<2>(A + (size_t)rowb * 768 + z * 384,
                  W + (size_t)colb * 768 + z * 384, 384, 768, 768,
                  As, Bs, acc);

  const int lane = threadIdx.x & 63, wid = threadIdx.x >> 6;
  const int lr = lane & 15, lq = lane >> 4;
  const int wr = (wid >> 1) * 64, wc = (wid & 1) * 64;
#pragma unroll
  for (int i = 0; i < 4; i++)
#pragma unroll
    for (int j = 0; j < 4; j++)
#pragma unroll
      for (int r = 0; r < 4; r++) {
        const int row = rowb + wr + i * 16 + lq * 4 + r;
        const int col = colb + wc + j * 16 + lr;
        atomicAdd(&Out[(size_t)row * 768 + col], acc[i][j][r]);
      }
}

// ---------------------------------------------------------------------------
// FFN2 split-K x4 (128^2 tiles, 1-barrier depth-3 + setprio): Out += 0.5*P.
// Out holds x1. grid (6,32,4), XCD-swizzled.
// ---------------------------------------------------------------------------
__global__ __launch_bounds__(256) void ffn2_splitk(
    const u16* __restrict__ H1, const u16* __restrict__ Ht,
    const u16* __restrict__ Hs, const u16* __restrict__ W2,
    const u16* __restrict__ W2t, const u16* __restrict__ W2s,
    float* __restrict__ Out) {
  __shared__ __align__(16) u16 As[384][32];
  __shared__ __align__(16) u16 Bs[384][32];
  const int w = xcd_work_id();
  const int bx = w % gridDim.x;
  const int by = (w / gridDim.x) % gridDim.y;
  const int z = w / (gridDim.x * gridDim.y);
  const int rowb = by * 128, colb = bx * 128;
  f32x4 acc[4][4] = {};
  if (z == 0)
    gemm128_loop<3>(H1 + (size_t)rowb * 3072, W2 + (size_t)colb * 3072,
                    1536, 3072, 3072, As, Bs, acc);
  else if (z == 1)
    gemm128_loop<3>(H1 + (size_t)rowb * 3072 + 1536,
                    W2 + (size_t)colb * 3072 + 1536,
                    1536, 3072, 3072, As, Bs, acc);
  else if (z == 2)
    gemm128_loop<3>(Ht + (size_t)rowb * 1536, W2t + (size_t)colb * 1536,
                    1536, 1536, 1536, As, Bs, acc);
  else
    gemm128_loop<3>(Hs + (size_t)rowb * 1536, W2s + (size_t)colb * 1536,
                    1536, 1536, 1536, As, Bs, acc);

  const int lane = threadIdx.x & 63, wid = threadIdx.x >> 6;
  const int lr = lane & 15, lq = lane >> 4;
  const int wr = (wid >> 1) * 64, wc = (wid & 1) * 64;
#pragma unroll
  for (int i = 0; i < 4; i++)
#pragma unroll
    for (int j = 0; j < 4; j++)
#pragma unroll
      for (int r = 0; r < 4; r++) {
        const int row = rowb + wr + i * 16 + lq * 4 + r;
        const int col = colb + wc + j * 16 + lr;
        atomicAdd(&Out[(size_t)row * 768 + col], 0.5f * acc[i][j][r]);
      }
}

// ---------------------------------------------------------------------------
// Flash attention producer, causal, KV-split chunk=4 (R22). QBLK=64, 4 waves.
// Per bh: 144 blocks. qt<4: writes final bf16. qt>=4: fp16 O partial +
// fp32 (m,l) at slot s = bh*140 + off(qt) + c.
// ---------------------------------------------------------------------------
__global__ __launch_bounds__(256) void flash_attn_k(
    const u16* __restrict__ Qc, const u16* __restrict__ Kb,
    const u16* __restrict__ Vb, u16* __restrict__ O,
    u16* __restrict__ Pn, u16* __restrict__ Ph, float* __restrict__ Lm) {
  __shared__ __align__(16) u16 Ks[64][40];
  __shared__ __align__(16) u16 Vt[64][72];
  __shared__ __align__(16) u16 Ps[4][16][72];
  const int tid = threadIdx.x, wid = tid >> 6, lane = tid & 63;
  const int lr = lane & 15, lq = lane >> 4;

  // decode blockIdx.x -> (qt, c); qt descending so long chunks launch first
  int bx = blockIdx.x, qt = 0, c = 0;
  for (int q = 31; q >= 0; --q) {
    const int nc = (q < 4) ? 1 : (q / 4 + 1);
    if (bx < nc) { qt = q; c = bx; break; }
    bx -= nc;
  }
  const int nt = qt + 1;
  const int t0 = c * 4;
  const int t1 = (t0 + 4 < nt) ? t0 + 4 : nt;

  const int qb = qt * 64;
  const int bh = blockIdx.y;
  const int b = bh / 12, h = bh % 12;
  const int q0 = qb + wid * 16;
  const size_t base = (size_t)b * 2048 * 768 + h * 64;

  bfrag aq[2];
  aq[0] = ldfrag(Qc + base + (size_t)(q0 + lr) * 768 + lq * 8);
  aq[1] = ldfrag(Qc + base + (size_t)(q0 + lr) * 768 + 32 + lq * 8);

  f32x4 o[4] = {};
  float mrow[4] = {NEG_BIG, NEG_BIG, NEG_BIG, NEG_BIG};
  float lrow[4] = {0.0f, 0.0f, 0.0f, 0.0f};

  const int krow = tid >> 3;        // 0..31
  const int kcol = (tid & 7) * 8;
  const int vkey = tid & 31;
  const int vdg = tid >> 5;         // 0..7

  const u16* kp = Kb + base + (size_t)(t0 * 64 + krow) * 768 + kcol;
  const u16* vp = Vb + base + (size_t)(t0 * 64 + vkey) * 768 + vdg * 8;

  uint4 kv0, kv1, vv0, vv1;
  __builtin_memcpy(&kv0, kp, 16);
  __builtin_memcpy(&kv1, kp + (size_t)32 * 768, 16);
  __builtin_memcpy(&vv0, vp, 16);
  __builtin_memcpy(&vv1, vp + (size_t)32 * 768, 16);

  for (int kt = t0; kt < t1; kt++) {
    __syncthreads();
    __builtin_memcpy(&Ks[krow][kcol], &kv0, 16);
    __builtin_memcpy(&Ks[krow + 32][kcol], &kv1, 16);
    {
      union { uint4 u; u16 s[8]; } a, b2;
      a.u = vv0; b2.u = vv1;
#pragma unroll
      for (int j = 0; j < 8; j++) {
        Vt[vdg * 8 + j][vkey] = a.s[j];
        Vt[vdg * 8 + j][vkey + 32] = b2.s[j];
      }
    }
    __syncthreads();
    if (kt + 1 < t1) {
      const size_t koff = (size_t)(kt + 1 - t0) * 64 * 768;
      __builtin_memcpy(&kv0, kp + koff, 16);
      __builtin_memcpy(&kv1, kp + koff + (size_t)32 * 768, 16);
      __builtin_memcpy(&vv0, vp + koff, 16);
      __builtin_memcpy(&vv1, vp + koff + (size_t)32 * 768, 16);
    }

    const int kbk = kt * 64;
    {
      f32x4 s4[4] = {};
#pragma unroll
      for (int kg = 0; kg < 2; kg++) {
#pragma unroll
        for (int cc = 0; cc < 4; cc++) {
          bfrag bk = ldfrag(&Ks[cc * 16 + lr][kg * 32 + lq * 8]);
          s4[cc] = MFMA(aq[kg], bk, s4[cc]);
        }
      }
#pragma unroll
      for (int r = 0; r < 4; r++) {
        const int q = q0 + lq * 4 + r;
        float v[4];
        float mx = NEG_BIG;
#pragma unroll
        for (int cc = 0; cc < 4; cc++) {
          v[cc] = (kbk + cc * 16 + lr > q) ? NEG_BIG : s4[cc][r];
          mx = fmaxf(mx, v[cc]);
        }
#pragma unroll
        for (int off = 8; off >= 1; off >>= 1)
          mx = fmaxf(mx, __shfl_xor(mx, off, 16));
        const float mn = fmaxf(mrow[r], mx);
        const float alpha = __expf(mrow[r] - mn);
        float sm = 0.0f;
        float p[4];
#pragma unroll
        for (int cc = 0; cc < 4; cc++) {
          p[cc] = __expf(v[cc] - mn);
          sm += p[cc];
        }
#pragma unroll
        for (int off = 8; off >= 1; off >>= 1) sm += __shfl_xor(sm, off, 16);
        lrow[r] = lrow[r] * alpha + sm;
        mrow[r] = mn;
#pragma unroll
        for (int dt = 0; dt < 4; dt++) o[dt][r] *= alpha;
#pragma unroll
        for (int cc = 0; cc < 4; cc++)
          Ps[wid][lq * 4 + r][cc * 16 + lr] = f2bf(p[cc]);
      }
      __threadfence_block();
      bfrag pf0 = ldfrag(&Ps[wid][lr][lq * 8]);
      bfrag pf1 = ldfrag(&Ps[wid][lr][32 + lq * 8]);
#pragma unroll
      for (int dt = 0; dt < 4; dt++) {
        bfrag v0 = ldfrag(&Vt[dt * 16 + lr][lq * 8]);
        bfrag v1 = ldfrag(&Vt[dt * 16 + lr][32 + lq * 8]);
        o[dt] = MFMA(pf0, v0, o[dt]);
        o[dt] = MFMA(pf1, v1, o[dt]);
      }
    }
  }

  if (qt < 4) {
    // final: normalize and write bf16
#pragma unroll
    for (int r = 0; r < 4; r++) {
      const float inv = 1.0f / fmaxf(lrow[r], 1e-30f);
      const int q = q0 + lq * 4 + r;
#pragma unroll
      for (int dt = 0; dt < 4; dt++)
        O[base + (size_t)q * 768 + dt * 16 + lr] = f2bf(o[dt][r] * inv);
    }
  } else {
    // partial: slot s = bh*140 + off(qt) + c
    int off = 0;
    for (int j = 4; j < qt; ++j) off += j / 4 + 1;
    const int s = bh * 140 + off + c;
    u16* Op = (s < 3072) ? Pn + (size_t)s * 4096
                         : Ph + (size_t)(s - 3072) * 4096;
    float* lmp = Lm + (size_t)s * 128;
#pragma unroll
    for (int r = 0; r < 4; r++) {
      const int row = wid * 16 + lq * 4 + r;
#pragma unroll
      for (int dt = 0; dt < 4; dt++)
        Op[(size_t)row * 64 + dt * 16 + lr] = f2h(o[dt][r]);
      if (lr == 0) { lmp[row] = mrow[r]; lmp[64 + row] = lrow[r]; }
    }
  }
}

// ---------------------------------------------------------------------------
// Merge partials for qt in [4,32): O = sum_c exp(m_c-m_g)*O_c / l_g.
// grid (28, 24): x = qt-4, y = bh. fp16 O partials, fp32 m/l.
// ---------------------------------------------------------------------------
__global__ __launch_bounds__(256) void attn_merge_k(
    const u16* __restrict__ Pn, const u16* __restrict__ Ph,
    const float* __restrict__ Lm, u16* __restrict__ O) {
  const int qt = 4 + blockIdx.x;
  const int bh = blockIdx.y;
  const int b = bh / 12, h = bh % 12;
  const int nc = qt / 4 + 1;
  int off = 0;
  for (int j = 4; j < qt; ++j) off += j / 4 + 1;
  const int s0 = bh * 140 + off;
  const int row = threadIdx.x >> 2;
  const int c0 = (threadIdx.x & 3) * 16;

  float mg = NEG_BIG;
  for (int cc = 0; cc < nc; ++cc)
    mg = fmaxf(mg, Lm[(size_t)(s0 + cc) * 128 + row]);

  float acc[16];
#pragma unroll
  for (int j = 0; j < 16; j++) acc[j] = 0.0f;
  float lg = 0.0f;
  for (int cc = 0; cc < nc; ++cc) {
    const int s = s0 + cc;
    const float mcv = Lm[(size_t)s * 128 + row];
    const float coef = __expf(mcv - mg);
    lg += coef * Lm[(size_t)s * 128 + 64 + row];
    const u16* Op = (s < 3072) ? Pn + (size_t)s * 4096
                               : Ph + (size_t)(s - 3072) * 4096;
    const u16* rp = Op + (size_t)row * 64 + c0;
    u16 tv[16];
    __builtin_memcpy(tv, rp, 32);
#pragma unroll
    for (int j = 0; j < 16; j++) acc[j] += coef * h2f(tv[j]);
  }
  const float inv = 1.0f / fmaxf(lg, 1e-30f);
  const int q = qt * 64 + row;
  const size_t ob = (size_t)b * 2048 * 768 + h * 64 + (size_t)q * 768 + c0;
#pragma unroll
  for (int j = 0; j < 16; j++) O[ob + j] = f2bf(acc[j] * inv);
}

// ---------------------------------------------------------------------------
extern "C" void kernel_launch(void* const* d_in, const int* in_sizes, int n_in,
                              void* d_out, int out_size, void* d_ws,
                              size_t ws_size, hipStream_t stream) {
  (void)in_sizes; (void)n_in; (void)out_size; (void)ws_size;
  const float* x = (const float*)d_in[0];
  const void* mask = d_in[2];

  char* ws = (char*)d_ws;
  u16* Wb  = (u16*)(ws);                        // bf16 arena, 23599104 B
  u16* n1h = (u16*)(ws + 23599104);             // 4096x3072 bf16 (h1 / attn partials)
  u16* Qb  = (u16*)(ws + 48764928);             // 4096x768 (later n2)
  u16* Kb2 = (u16*)(ws + 55056384);             // 4096x768
  u16* Vb2 = (u16*)(ws + 61347840);             // 4096x768
  u16* att = (u16*)(ws + 67639296);             // 4096x768 att, later ht (x1536)
  u16* hs  = (u16*)(ws + 80222208);             // 4096x1536 (attn partial spill)
  float* mfl = (float*)(ws + 92805120);         // 768 floats
  float* x1 = (float*)d_out;                    // x / x1 fp32 live in d_out
  u16* Pn16 = n1h;                              // fp16 O-partials, slots 0..3071
  u16* Ph16 = hs;                               // fp16 O-partials, slots 3072..3359
  float* Lm = (float*)(ws + 80222208 + 4194304); // m/l: 3360 slots x 128 f32

  u16* Wq = Wb + 0,        *Wk = Wb + 589824,   *Wv = Wb + 1179648;
  u16* Wo = Wb + 1769472,  *w1 = Wb + 2359296,  *w1t = Wb + 4718592;
  u16* w1s = Wb + 5898240, *w2 = Wb + 7077888,  *w2t = Wb + 9437184;
  u16* w2s = Wb + 10616832;
  u16* n1w = Wb + 11796480, *n1b = Wb + 11797248;
  u16* n2w = Wb + 11798016, *n2b = Wb + 11798784;

  Segs sg;
  const int srcidx[14] = {3, 4, 5, 6, 7, 9, 11, 8, 10, 12, 13, 14, 15, 16};
  const int offs[14] = {0, 589824, 1179648, 1769472, 2359296, 4718592,
                        5898240, 7077888, 9437184, 10616832,
                        11796480, 11797248, 11798016, 11798784};
  const int ns[14] = {589824, 589824, 589824, 589824, 2359296, 1179648,
                      1179648, 2359296, 1179648, 1179648, 768, 768, 768, 768};
  const int mms[14] = {0, 0, 0, 0, 0, 1, 2, 0, 0, 0, 0, 0, 0, 0};
  int tot = 0;
  for (int i = 0; i < 14; i++) {
    sg.src[i] = d_in[srcidx[i]];
    sg.off[i] = offs[i];
    sg.n[i] = ns[i];
    sg.mmode[i] = mms[i];
    sg.blk0[i] = tot;
    tot += (ns[i] + 1023) / 1024;
  }
  sg.blk0[14] = tot;   // 11524

  mask_conv_k<<<1, 256, 0, stream>>>(mask, mfl);
  convert_k<<<tot, 256, 0, stream>>>(sg, Wb, mfl);

  // n1 = mink_norm(x); also seed d_out with x (residual base for Wo atomics)
  mink_norm_k<<<4096, 256, 0, stream>>>(x, mfl, n1w, n1b, n1h, x1);

  // Q,K,V fused (N=2304), XCD-swizzled, 2-barrier loop. seg0: fused qcorr.
  GArgs qkv;
  qkv.s[0] = {Wq, Qb, 768, 6, 1};
  qkv.s[1] = {Wk, Kb2, 768, 6, 0};
  qkv.s[2] = {Wv, Vb2, 768, 6, 0};
  gemm128_fused<<<dim3(18, 32), 256, 0, stream>>>(n1h, 768, 768, qkv, mfl);

  // flash attention: 144 chunks/bh (chunk=4 kv-tiles), fp16 partials, merge
  flash_attn_k<<<dim3(144, 24), 256, 0, stream>>>(Qb, Kb2, Vb2, att,
                                                  Pn16, Ph16, Lm);
  attn_merge_k<<<dim3(28, 24), 256, 0, stream>>>(Pn16, Ph16, Lm, att);

  // x1 = x + att @ Wo^T  (split-K x2 atomic, 2-barrier loop)
  gemm128_wo_splitk<<<dim3(6, 32, 2), 256, 0, stream>>>(att, Wo, x1);

  // n2 = mink_norm(x1) -> Qb (mask folded into FFN1 weights)
  mink_norm_k<<<4096, 256, 0, stream>>>(x1, mfl, n2w, n2b, Qb, nullptr);

  // FFN1 fused (N=6144), 2-barrier loop (keeps 5 blocks/CU occupancy)
  GArgs ffn1;
  ffn1.s[0] = {w1, n1h, 3072, 24, 2};
  ffn1.s[1] = {w1t, att, 1536, 12, 3};
  ffn1.s[2] = {w1s, hs, 1536, 12, 2};
  gemm128_fused<<<dim3(48, 32), 256, 0, stream>>>(Qb, 768, 768, ffn1, mfl);

  // out = x1 + 0.5*(h1@w2^T + ht@w2_t^T + hs@w2_s^T), x4 atomic, 1-barrier
  ffn2_splitk<<<dim3(6, 32, 4), 256, 0, stream>>>(n1h, att, hs, w2, w2t, w2s,
                                                  (float*)d_out);
}